// Round 1
// baseline (1903.754 us; speedup 1.0000x reference)
//
#include <hip/hip_runtime.h>
#include <cstdint>

#define DEVI __device__ __forceinline__

typedef short v8s __attribute__((ext_vector_type(8)));
typedef float v4f __attribute__((ext_vector_type(4)));

DEVI short f2bf(float f){
  uint32_t u = __builtin_bit_cast(uint32_t, f);
  u += 0x7FFF + ((u >> 16) & 1);          // round-to-nearest-even
  return (short)(u >> 16);
}

DEVI void gload16(const void* g, void* l){
  __builtin_amdgcn_global_load_lds(
      (const __attribute__((address_space(1))) unsigned*)g,
      (__attribute__((address_space(3))) unsigned*)l, 16, 0, 0);
}

// ---------------------------------------------------------------- LayerNorm
template<bool BF16OUT>
__global__ __launch_bounds__(256) void ln_kernel(
    const float* __restrict__ x, const float* __restrict__ w,
    const float* __restrict__ b, void* __restrict__ out)
{
  const int row = blockIdx.x;
  const int t = threadIdx.x;
  const float4 v = ((const float4*)(x + (size_t)row * 1024))[t];
  float s  = v.x + v.y + v.z + v.w;
  float s2 = v.x*v.x + v.y*v.y + v.z*v.z + v.w*v.w;
  #pragma unroll
  for (int m = 1; m < 64; m <<= 1){ s += __shfl_xor(s, m); s2 += __shfl_xor(s2, m); }
  __shared__ float ps[4], ps2[4];
  if ((t & 63) == 0){ ps[t >> 6] = s; ps2[t >> 6] = s2; }
  __syncthreads();
  s  = ps[0] + ps[1] + ps[2] + ps[3];
  s2 = ps2[0] + ps2[1] + ps2[2] + ps2[3];
  const float mu = s * (1.f / 1024.f);
  const float rs = rsqrtf(s2 * (1.f / 1024.f) - mu * mu + 1e-5f);
  const float4 wv = ((const float4*)w)[t];
  const float4 bv = ((const float4*)b)[t];
  const float o0 = (v.x - mu) * rs * wv.x + bv.x;
  const float o1 = (v.y - mu) * rs * wv.y + bv.y;
  const float o2 = (v.z - mu) * rs * wv.z + bv.z;
  const float o3 = (v.w - mu) * rs * wv.w + bv.w;
  if (BF16OUT){
    uint2 pk;
    pk.x = (uint16_t)f2bf(o0) | ((uint32_t)(uint16_t)f2bf(o1) << 16);
    pk.y = (uint16_t)f2bf(o2) | ((uint32_t)(uint16_t)f2bf(o3) << 16);
    ((uint2*)out)[(size_t)row * 256 + t] = pk;
  } else {
    ((float4*)out)[(size_t)row * 256 + t] = make_float4(o0, o1, o2, o3);
  }
}

// ------------------------------------------- weight fp32[K][N] -> bf16[N][K]
__global__ __launch_bounds__(256) void wconv(
    const float* __restrict__ W, short* __restrict__ Wt, int K, int N)
{
  __shared__ float t[32][33];
  const int n0 = blockIdx.x * 32, k0 = blockIdx.y * 32;
  const int c = threadIdx.x & 31, r = threadIdx.x >> 5;   // r in 0..7
  #pragma unroll
  for (int i = 0; i < 4; ++i)
    t[r + i*8][c] = W[(size_t)(k0 + r + i*8) * N + n0 + c];
  __syncthreads();
  #pragma unroll
  for (int i = 0; i < 4; ++i)
    Wt[(size_t)(n0 + r + i*8) * K + k0 + c] = f2bf(t[c][r + i*8]);
}

// ---------------------------------------------------------------- GEMM
// A: bf16 [M][K] row-major.  Bt: bf16 [N][K] (weight pre-transposed).
// EPI 0: out bf16 = acc + qkv-bias(b0/b1/b2 by col segment of 1024)
// EPI 1: out f32  = resid + acc + b0[col]
// EPI 2: out bf16 = gelu(acc + b0[col])
template<int MF, int NF, int EPI>
__global__ __launch_bounds__(256) void gemm_kernel(
    const short* __restrict__ A, const short* __restrict__ Bt,
    void* __restrict__ out, const float* __restrict__ resid,
    const float* __restrict__ b0, const float* __restrict__ b1,
    const float* __restrict__ b2, int M, int N, int K)
{
  constexpr int BM = 32 * MF, BN = 32 * NF;
  __shared__ __attribute__((aligned(16))) short a_t[BM * 64];
  __shared__ __attribute__((aligned(16))) short b_t[BN * 64];
  const int tid = threadIdx.x;
  const int l = tid & 63, w = tid >> 6;
  const int m0 = blockIdx.y * BM, n0 = blockIdx.x * BN;
  const int lr = l >> 3;            // staging: row within 8-row group
  const int lc = (l & 7) * 8;       // staging: col start (bf16 elems)
  const int wm = w >> 1, wn = w & 1;
  const int fr = l & 15;            // fragment M-row / N-col index
  const int fko = (l >> 4) * 8;     // fragment K offset (contiguous 8)

  const v4f vz = {0.f, 0.f, 0.f, 0.f};
  v4f acc[MF][NF];
  #pragma unroll
  for (int i = 0; i < MF; ++i)
    #pragma unroll
    for (int j = 0; j < NF; ++j) acc[i][j] = vz;

  for (int kt = 0; kt < K; kt += 64){
    __syncthreads();
    #pragma unroll
    for (int j = 0; j < BM / 32; ++j){
      const int rbase = (j * 4 + w) * 8;
      gload16(A + (size_t)(m0 + rbase + lr) * K + kt + lc, a_t + rbase * 64);
    }
    #pragma unroll
    for (int j = 0; j < BN / 32; ++j){
      const int rbase = (j * 4 + w) * 8;
      gload16(Bt + (size_t)(n0 + rbase + lr) * K + kt + lc, b_t + rbase * 64);
    }
    __syncthreads();
    #pragma unroll
    for (int ks = 0; ks < 2; ++ks){
      const int co = ks * 32 + fko;
      v8s af[MF], bf[NF];
      #pragma unroll
      for (int mf = 0; mf < MF; ++mf)
        af[mf] = *(const v8s*)(a_t + (wm * MF * 16 + mf * 16 + fr) * 64 + co);
      #pragma unroll
      for (int nf = 0; nf < NF; ++nf)
        bf[nf] = *(const v8s*)(b_t + (wn * NF * 16 + nf * 16 + fr) * 64 + co);
      #pragma unroll
      for (int mf = 0; mf < MF; ++mf)
        #pragma unroll
        for (int nf = 0; nf < NF; ++nf)
          acc[mf][nf] = __builtin_amdgcn_mfma_f32_16x16x32_bf16(
              af[mf], bf[nf], acc[mf][nf], 0, 0, 0);
    }
  }

  #pragma unroll
  for (int mf = 0; mf < MF; ++mf){
    #pragma unroll
    for (int nf = 0; nf < NF; ++nf){
      const int col = n0 + wn * NF * 16 + nf * 16 + fr;
      float bias;
      if (EPI == 0)
        bias = col < 1024 ? b0[col] : (col < 2048 ? b1[col - 1024] : b2[col - 2048]);
      else
        bias = b0[col];
      #pragma unroll
      for (int r = 0; r < 4; ++r){
        const int row = m0 + wm * MF * 16 + mf * 16 + (l >> 4) * 4 + r;
        const float v = acc[mf][nf][r] + bias;
        if (EPI == 0){
          ((short*)out)[(size_t)row * N + col] = f2bf(v);
        } else if (EPI == 1){
          ((float*)out)[(size_t)row * N + col] =
              resid[(size_t)row * N + col] + v;
        } else {
          const float g = 0.5f * v * (1.0f + erff(v * 0.70710678118f));
          ((short*)out)[(size_t)row * N + col] = f2bf(g);
        }
      }
    }
  }
}

// ---------------------------------------------------------------- Attention
// qkv: bf16 [2048][3072] rows = b*1024+t, cols: q[0:1024) k[1024:2048) v[2048:3072)
// per head hh: 64 dims at hh*64. Block-causal TPB=64: query block qb sees key
// blocks 0..qb fully (no element masking). 4 waves, wave w owns q-rows w*16..+15.
__global__ __launch_bounds__(256) void attn_kernel(
    const short* __restrict__ qkv, short* __restrict__ y)
{
  const int qb = blockIdx.x, hh = blockIdx.y, b = blockIdx.z;
  const int tid = threadIdx.x, l = tid & 63, w = tid >> 6;
  __shared__ __attribute__((aligned(16))) short vt[64 * 72];      // V^T [d][s], padded
  __shared__ __attribute__((aligned(16))) short pl[4][16 * 72];   // per-wave P strip

  const int fr = l & 15;
  const int fko = (l >> 4) * 8;
  const size_t qrow = (size_t)(b * 1024 + qb * 64 + w * 16 + fr) * 3072 + hh * 64 + fko;
  const v8s qf0 = *(const v8s*)(qkv + qrow);
  const v8s qf1 = *(const v8s*)(qkv + qrow + 32);

  const v4f vz = {0.f, 0.f, 0.f, 0.f};
  v4f o[4] = {vz, vz, vz, vz};
  float mrow[4] = {-1e30f, -1e30f, -1e30f, -1e30f};
  float lrow[4] = {0.f, 0.f, 0.f, 0.f};

  const int vd0 = (tid & 7) * 8, vs0 = (tid >> 3) * 2;

  for (int kvb = 0; kvb <= qb; ++kvb){
    __syncthreads();   // protect vt overwrite vs prior iter's reads
    {
      const short* vsrc = qkv + (size_t)(b * 1024 + kvb * 64 + vs0) * 3072
                          + 2048 + hh * 64 + vd0;
      const v8s r0 = *(const v8s*)vsrc;
      const v8s r1 = *(const v8s*)(vsrc + 3072);
      #pragma unroll
      for (int j = 0; j < 8; ++j){
        const uint32_t pk = (uint16_t)r0[j] | ((uint32_t)(uint16_t)r1[j] << 16);
        *(uint32_t*)(vt + (vd0 + j) * 72 + vs0) = pk;
      }
    }
    __syncthreads();

    // S = Q K^T (16 q-rows x 64 keys per wave), K fragments direct from global
    v4f s[4] = {vz, vz, vz, vz};
    #pragma unroll
    for (int nf = 0; nf < 4; ++nf){
      const short* kp = qkv + (size_t)(b * 1024 + kvb * 64 + nf * 16 + fr) * 3072
                        + 1024 + hh * 64 + fko;
      const v8s kb0 = *(const v8s*)kp;
      const v8s kb1 = *(const v8s*)(kp + 32);
      s[nf] = __builtin_amdgcn_mfma_f32_16x16x32_bf16(qf0, kb0, s[nf], 0, 0, 0);
      s[nf] = __builtin_amdgcn_mfma_f32_16x16x32_bf16(qf1, kb1, s[nf], 0, 0, 0);
    }
    #pragma unroll
    for (int nf = 0; nf < 4; ++nf)
      #pragma unroll
      for (int r = 0; r < 4; ++r) s[nf][r] *= 0.125f;

    // online softmax: lane's 4 rows are t_local=(l>>4)*4+r; row-reduce over
    // the 16 lanes sharing l>>4 (xor 1,2,4,8)
    #pragma unroll
    for (int r = 0; r < 4; ++r){
      float mx = fmaxf(fmaxf(s[0][r], s[1][r]), fmaxf(s[2][r], s[3][r]));
      mx = fmaxf(mx, __shfl_xor(mx, 1));
      mx = fmaxf(mx, __shfl_xor(mx, 2));
      mx = fmaxf(mx, __shfl_xor(mx, 4));
      mx = fmaxf(mx, __shfl_xor(mx, 8));
      const float mn = fmaxf(mrow[r], mx);
      const float fac = __expf(mrow[r] - mn);
      float rs = 0.f;
      #pragma unroll
      for (int nf = 0; nf < 4; ++nf){ s[nf][r] = __expf(s[nf][r] - mn); rs += s[nf][r]; }
      rs += __shfl_xor(rs, 1);
      rs += __shfl_xor(rs, 2);
      rs += __shfl_xor(rs, 4);
      rs += __shfl_xor(rs, 8);
      lrow[r] = lrow[r] * fac + rs;
      mrow[r] = mn;
      #pragma unroll
      for (int nf = 0; nf < 4; ++nf) o[nf][r] *= fac;
    }

    // P (C-layout) -> LDS strip [16][72] so it can be re-read as A-fragments
    #pragma unroll
    for (int nf = 0; nf < 4; ++nf)
      #pragma unroll
      for (int r = 0; r < 4; ++r)
        pl[w][((l >> 4) * 4 + r) * 72 + nf * 16 + fr] = f2bf(s[nf][r]);
    __syncthreads();   // order P writes (cross-lane) before A-frag reads

    // O += P @ V
    #pragma unroll
    for (int ks = 0; ks < 2; ++ks){
      const v8s pa = *(const v8s*)(pl[w] + fr * 72 + ks * 32 + fko);
      #pragma unroll
      for (int nf = 0; nf < 4; ++nf){
        const v8s vb = *(const v8s*)(vt + (nf * 16 + fr) * 72 + ks * 32 + fko);
        o[nf] = __builtin_amdgcn_mfma_f32_16x16x32_bf16(pa, vb, o[nf], 0, 0, 0);
      }
    }
  }

  #pragma unroll
  for (int r = 0; r < 4; ++r){
    const float inv = 1.0f / lrow[r];
    #pragma unroll
    for (int nf = 0; nf < 4; ++nf) o[nf][r] *= inv;
  }
  #pragma unroll
  for (int nf = 0; nf < 4; ++nf)
    #pragma unroll
    for (int r = 0; r < 4; ++r){
      const int row = b * 1024 + qb * 64 + w * 16 + (l >> 4) * 4 + r;
      y[(size_t)row * 1024 + hh * 64 + nf * 16 + fr] = f2bf(o[nf][r]);
    }
}

// ---------------------------------------------------------------- launch
extern "C" void kernel_launch(void* const* d_in, const int* in_sizes, int n_in,
                              void* d_out, int out_size, void* d_ws, size_t ws_size,
                              hipStream_t stream)
{
  const float* seq  = (const float*)d_in[0];
  const float* ln1w = (const float*)d_in[1];
  const float* ln1b = (const float*)d_in[2];
  const float* Wq   = (const float*)d_in[3];
  const float* bq   = (const float*)d_in[4];
  const float* Wk   = (const float*)d_in[5];
  const float* bk   = (const float*)d_in[6];
  const float* Wv   = (const float*)d_in[7];
  const float* bv   = (const float*)d_in[8];
  const float* Wp   = (const float*)d_in[9];
  const float* bp   = (const float*)d_in[10];
  const float* ln2w = (const float*)d_in[11];
  const float* ln2b = (const float*)d_in[12];
  const float* W1   = (const float*)d_in[13];
  const float* b1   = (const float*)d_in[14];
  const float* W2   = (const float*)d_in[15];
  const float* b2   = (const float*)d_in[16];
  const float* lnfw = (const float*)d_in[17];
  const float* lnfb = (const float*)d_in[18];

  char* p = (char*)d_ws;
  auto carve = [&](size_t bytes){
    void* r = (void*)p;
    p += (bytes + 255) & ~(size_t)255;
    return r;
  };
  short* wtQKV = (short*)carve((size_t)3072 * 1024 * 2);   // [3072][1024]
  short* wtP   = (short*)carve((size_t)1024 * 1024 * 2);   // [1024][1024]
  short* wt1   = (short*)carve((size_t)4096 * 1024 * 2);   // [4096][1024]
  short* wt2   = (short*)carve((size_t)1024 * 4096 * 2);   // [1024][4096]
  float* x     = (float*)carve((size_t)2048 * 1024 * 4);
  short* h     = (short*)carve((size_t)2048 * 1024 * 2);
  short* qkv   = (short*)carve((size_t)2048 * 3072 * 2);
  short* y     = (short*)carve((size_t)2048 * 1024 * 2);
  short* hm    = (short*)carve((size_t)2048 * 4096 * 2);

  for (int l = 0; l < 8; ++l){
    wconv<<<dim3(32, 32),  256, 0, stream>>>(Wq + (size_t)l * 1048576, wtQKV,               1024, 1024);
    wconv<<<dim3(32, 32),  256, 0, stream>>>(Wk + (size_t)l * 1048576, wtQKV + 1048576,     1024, 1024);
    wconv<<<dim3(32, 32),  256, 0, stream>>>(Wv + (size_t)l * 1048576, wtQKV + 2 * 1048576, 1024, 1024);
    wconv<<<dim3(32, 32),  256, 0, stream>>>(Wp + (size_t)l * 1048576, wtP, 1024, 1024);
    wconv<<<dim3(128, 32), 256, 0, stream>>>(W1 + (size_t)l * 4194304, wt1, 1024, 4096);
    wconv<<<dim3(32, 128), 256, 0, stream>>>(W2 + (size_t)l * 4194304, wt2, 4096, 1024);

    const float* xin = (l == 0) ? seq : x;
    ln_kernel<true><<<2048, 256, 0, stream>>>(xin, ln1w + l * 1024, ln1b + l * 1024, h);
    gemm_kernel<4, 4, 0><<<dim3(24, 16), 256, 0, stream>>>(
        h, wtQKV, qkv, nullptr, bq + l * 1024, bk + l * 1024, bv + l * 1024,
        2048, 3072, 1024);
    attn_kernel<<<dim3(16, 16, 2), 256, 0, stream>>>(qkv, y);
    gemm_kernel<2, 4, 1><<<dim3(8, 32), 256, 0, stream>>>(
        y, wtP, x, xin, bp + l * 1024, nullptr, nullptr, 2048, 1024, 1024);
    ln_kernel<true><<<2048, 256, 0, stream>>>(x, ln2w + l * 1024, ln2b + l * 1024, h);
    gemm_kernel<4, 4, 2><<<dim3(32, 16), 256, 0, stream>>>(
        h, wt1, hm, nullptr, b1 + l * 4096, nullptr, nullptr, 2048, 4096, 1024);
    gemm_kernel<2, 4, 1><<<dim3(8, 32), 256, 0, stream>>>(
        hm, wt2, x, x, b2 + l * 1024, nullptr, nullptr, 2048, 1024, 4096);
  }
  ln_kernel<false><<<2048, 256, 0, stream>>>(x, lnfw, lnfb, d_out);
}

// Round 2
// 1898.368 us; speedup vs baseline: 1.0028x; 1.0028x over previous
//
#include <hip/hip_runtime.h>
#include <cstdint>

#define DEVI __device__ __forceinline__

typedef short v8s __attribute__((ext_vector_type(8)));
typedef float v4f __attribute__((ext_vector_type(4)));

DEVI short f2bf(float f){
  uint32_t u = __builtin_bit_cast(uint32_t, f);
  u += 0x7FFF + ((u >> 16) & 1);          // round-to-nearest-even
  return (short)(u >> 16);
}
DEVI float bf2f(short s){
  uint32_t u = ((uint32_t)(uint16_t)s) << 16;
  return __builtin_bit_cast(float, u);
}

DEVI void gload16(const void* g, void* l){
  __builtin_amdgcn_global_load_lds(
      (const __attribute__((address_space(1))) unsigned*)g,
      (__attribute__((address_space(3))) unsigned*)l, 16, 0, 0);
}

// ---------------------------------------------------------------- LayerNorm
template<bool BF16OUT>
__global__ __launch_bounds__(256) void ln_kernel(
    const float* __restrict__ x, const float* __restrict__ w,
    const float* __restrict__ b, void* __restrict__ out)
{
  const int row = blockIdx.x;
  const int t = threadIdx.x;
  const float4 v = ((const float4*)(x + (size_t)row * 1024))[t];
  float s  = v.x + v.y + v.z + v.w;
  float s2 = v.x*v.x + v.y*v.y + v.z*v.z + v.w*v.w;
  #pragma unroll
  for (int m = 1; m < 64; m <<= 1){ s += __shfl_xor(s, m); s2 += __shfl_xor(s2, m); }
  __shared__ float ps[4], ps2[4];
  if ((t & 63) == 0){ ps[t >> 6] = s; ps2[t >> 6] = s2; }
  __syncthreads();
  s  = ps[0] + ps[1] + ps[2] + ps[3];
  s2 = ps2[0] + ps2[1] + ps2[2] + ps2[3];
  const float mu = s * (1.f / 1024.f);
  const float rs = rsqrtf(s2 * (1.f / 1024.f) - mu * mu + 1e-5f);
  const float4 wv = ((const float4*)w)[t];
  const float4 bv = ((const float4*)b)[t];
  const float o0 = (v.x - mu) * rs * wv.x + bv.x;
  const float o1 = (v.y - mu) * rs * wv.y + bv.y;
  const float o2 = (v.z - mu) * rs * wv.z + bv.z;
  const float o3 = (v.w - mu) * rs * wv.w + bv.w;
  if (BF16OUT){
    uint2 pk;
    pk.x = (uint16_t)f2bf(o0) | ((uint32_t)(uint16_t)f2bf(o1) << 16);
    pk.y = (uint16_t)f2bf(o2) | ((uint32_t)(uint16_t)f2bf(o3) << 16);
    ((uint2*)out)[(size_t)row * 256 + t] = pk;
  } else {
    ((float4*)out)[(size_t)row * 256 + t] = make_float4(o0, o1, o2, o3);
  }
}

// ---------------- weight fp32[L][K][N] -> bf16[L][N][K], 64x64 tiles, z=layer
__global__ __launch_bounds__(256) void wconv64(
    const float* __restrict__ W, short* __restrict__ Wt,
    int K, int N, size_t in_lstride, size_t out_lstride)
{
  __shared__ float t[64][65];
  const int n0 = blockIdx.x * 64, k0 = blockIdx.y * 64;
  const float* Wl = W + (size_t)blockIdx.z * in_lstride;
  short* Wtl = Wt + (size_t)blockIdx.z * out_lstride;
  const int tid = threadIdx.x;
  const int c4 = (tid & 15) * 4, r = tid >> 4;
  #pragma unroll
  for (int i = 0; i < 4; ++i){
    const float4 v = *(const float4*)(Wl + (size_t)(k0 + r + i*16) * N + n0 + c4);
    t[r + i*16][c4 + 0] = v.x;
    t[r + i*16][c4 + 1] = v.y;
    t[r + i*16][c4 + 2] = v.z;
    t[r + i*16][c4 + 3] = v.w;
  }
  __syncthreads();
  #pragma unroll
  for (int i = 0; i < 4; ++i){
    const int n = r + i*16;
    short4 s;
    s.x = f2bf(t[c4 + 0][n]);
    s.y = f2bf(t[c4 + 1][n]);
    s.z = f2bf(t[c4 + 2][n]);
    s.w = f2bf(t[c4 + 3][n]);
    *(short4*)(Wtl + (size_t)(n0 + n) * K + k0 + c4) = s;
  }
}

// ---------------------------------------------------------------- GEMM
// A: bf16 [M][K] row-major.  Bt: bf16 [N][K] (weight pre-transposed).
// EPI 0: out bf16 = acc + qkv-bias(b0/b1/b2 by col segment of 1024)
// EPI 1: out f32  = resid + acc + b0[col]
// EPI 2: out bf16 = gelu(acc + b0[col])
template<int MF, int NF, int EPI>
__global__ __launch_bounds__(256) void gemm_kernel(
    const short* __restrict__ A, const short* __restrict__ Bt,
    void* __restrict__ out, const float* __restrict__ resid,
    const float* __restrict__ b0, const float* __restrict__ b1,
    const float* __restrict__ b2, int M, int N, int K)
{
  constexpr int BM = 32 * MF, BN = 32 * NF;
  __shared__ __attribute__((aligned(16))) short a_t[BM * 64];
  __shared__ __attribute__((aligned(16))) short b_t[BN * 64];
  const int tid = threadIdx.x;
  const int l = tid & 63, w = tid >> 6;
  const int m0 = blockIdx.y * BM, n0 = blockIdx.x * BN;
  const int lr = l >> 3;            // staging: row within 8-row group
  const int lc = (l & 7) * 8;       // staging: col start (bf16 elems)
  const int wm = w >> 1, wn = w & 1;
  const int fr = l & 15;            // fragment M-row / N-col index
  const int fko = (l >> 4) * 8;     // fragment K offset (contiguous 8)

  const v4f vz = {0.f, 0.f, 0.f, 0.f};
  v4f acc[MF][NF];
  #pragma unroll
  for (int i = 0; i < MF; ++i)
    #pragma unroll
    for (int j = 0; j < NF; ++j) acc[i][j] = vz;

  for (int kt = 0; kt < K; kt += 64){
    __syncthreads();
    #pragma unroll
    for (int j = 0; j < BM / 32; ++j){
      const int rbase = (j * 4 + w) * 8;
      gload16(A + (size_t)(m0 + rbase + lr) * K + kt + lc, a_t + rbase * 64);
    }
    #pragma unroll
    for (int j = 0; j < BN / 32; ++j){
      const int rbase = (j * 4 + w) * 8;
      gload16(Bt + (size_t)(n0 + rbase + lr) * K + kt + lc, b_t + rbase * 64);
    }
    __syncthreads();
    #pragma unroll
    for (int ks = 0; ks < 2; ++ks){
      const int co = ks * 32 + fko;
      v8s af[MF], bf[NF];
      #pragma unroll
      for (int mf = 0; mf < MF; ++mf)
        af[mf] = *(const v8s*)(a_t + (wm * MF * 16 + mf * 16 + fr) * 64 + co);
      #pragma unroll
      for (int nf = 0; nf < NF; ++nf)
        bf[nf] = *(const v8s*)(b_t + (wn * NF * 16 + nf * 16 + fr) * 64 + co);
      #pragma unroll
      for (int mf = 0; mf < MF; ++mf)
        #pragma unroll
        for (int nf = 0; nf < NF; ++nf)
          acc[mf][nf] = __builtin_amdgcn_mfma_f32_16x16x32_bf16(
              af[mf], bf[nf], acc[mf][nf], 0, 0, 0);
    }
  }

  #pragma unroll
  for (int mf = 0; mf < MF; ++mf){
    #pragma unroll
    for (int nf = 0; nf < NF; ++nf){
      const int col = n0 + wn * NF * 16 + nf * 16 + fr;
      float bias;
      if (EPI == 0)
        bias = col < 1024 ? b0[col] : (col < 2048 ? b1[col - 1024] : b2[col - 2048]);
      else
        bias = b0[col];
      #pragma unroll
      for (int r = 0; r < 4; ++r){
        const int row = m0 + wm * MF * 16 + mf * 16 + (l >> 4) * 4 + r;
        const float v = acc[mf][nf][r] + bias;
        if (EPI == 0){
          ((short*)out)[(size_t)row * N + col] = f2bf(v);
        } else if (EPI == 1){
          ((float*)out)[(size_t)row * N + col] =
              resid[(size_t)row * N + col] + v;
        } else {
          const float g = 0.5f * v * (1.0f + erff(v * 0.70710678118f));
          ((short*)out)[(size_t)row * N + col] = f2bf(g);
        }
      }
    }
  }
}

// ---------------------------------------------------------------- Attention
// qkv: bf16 [2048][3072] rows = b*1024+t, cols: q[0:1024) k[1024:2048) v[2048:3072)
// Block-causal TPB=64: query block qb sees key blocks 0..qb fully (no element
// masking). 4 waves, wave w owns q-rows w*16..+15. One barrier per kv-iter:
// vt double-buffered (write of buf i+2 is after barrier i+1 which follows all
// iter-i reads); pl strip is same-wave-only (lgkmcnt dependency, no barrier).
__global__ __launch_bounds__(256) void attn_kernel(
    const short* __restrict__ qkv, short* __restrict__ y)
{
  const int qb = blockIdx.x, hh = blockIdx.y, b = blockIdx.z;
  const int tid = threadIdx.x, l = tid & 63, w = tid >> 6;
  __shared__ __attribute__((aligned(16))) short vt[2][64 * 72];   // V^T [d][s], padded
  __shared__ __attribute__((aligned(16))) short pl[4][16 * 72];   // per-wave P strip

  const int fr = l & 15;
  const int fko = (l >> 4) * 8;
  const size_t qrow = (size_t)(b * 1024 + qb * 64 + w * 16 + fr) * 3072 + hh * 64 + fko;
  // Q fragment pre-scaled by 1/sqrt(64)=0.125 (power of two: exact in bf16)
  v8s qf0, qf1;
  {
    const v8s q0 = *(const v8s*)(qkv + qrow);
    const v8s q1 = *(const v8s*)(qkv + qrow + 32);
    #pragma unroll
    for (int j = 0; j < 8; ++j){
      qf0[j] = f2bf(bf2f(q0[j]) * 0.125f);
      qf1[j] = f2bf(bf2f(q1[j]) * 0.125f);
    }
  }

  const v4f vz = {0.f, 0.f, 0.f, 0.f};
  v4f o[4] = {vz, vz, vz, vz};
  float mrow[4] = {-1e30f, -1e30f, -1e30f, -1e30f};
  float lrow[4] = {0.f, 0.f, 0.f, 0.f};

  const int vd0 = (tid & 7) * 8, vs0 = (tid >> 3) * 2;
  const short* kbase = qkv + (size_t)(b * 1024) * 3072 + 1024 + hh * 64 + fko;

  for (int kvb = 0; kvb <= qb; ++kvb){
    short* vcur = vt[kvb & 1];
    {
      const short* vsrc = qkv + (size_t)(b * 1024 + kvb * 64 + vs0) * 3072
                          + 2048 + hh * 64 + vd0;
      const v8s r0 = *(const v8s*)vsrc;
      const v8s r1 = *(const v8s*)(vsrc + 3072);
      #pragma unroll
      for (int j = 0; j < 8; ++j){
        const uint32_t pk = (uint16_t)r0[j] | ((uint32_t)(uint16_t)r1[j] << 16);
        *(uint32_t*)(vcur + (vd0 + j) * 72 + vs0) = pk;
      }
    }
    __syncthreads();

    // S = Q K^T (16 q-rows x 64 keys per wave), K fragments direct from global
    v4f s[4] = {vz, vz, vz, vz};
    #pragma unroll
    for (int nf = 0; nf < 4; ++nf){
      const short* kp = kbase + (size_t)(kvb * 64 + nf * 16 + fr) * 3072;
      const v8s kb0 = *(const v8s*)kp;
      const v8s kb1 = *(const v8s*)(kp + 32);
      s[nf] = __builtin_amdgcn_mfma_f32_16x16x32_bf16(qf0, kb0, s[nf], 0, 0, 0);
      s[nf] = __builtin_amdgcn_mfma_f32_16x16x32_bf16(qf1, kb1, s[nf], 0, 0, 0);
    }

    // online softmax: lane's 4 rows are t_local=(l>>4)*4+r; row-reduce over
    // the 16 lanes sharing l>>4 (xor 1,2,4,8)
    #pragma unroll
    for (int r = 0; r < 4; ++r){
      float mx = fmaxf(fmaxf(s[0][r], s[1][r]), fmaxf(s[2][r], s[3][r]));
      mx = fmaxf(mx, __shfl_xor(mx, 1));
      mx = fmaxf(mx, __shfl_xor(mx, 2));
      mx = fmaxf(mx, __shfl_xor(mx, 4));
      mx = fmaxf(mx, __shfl_xor(mx, 8));
      const float mn = fmaxf(mrow[r], mx);
      const float fac = __expf(mrow[r] - mn);
      float rs = 0.f;
      #pragma unroll
      for (int nf = 0; nf < 4; ++nf){ s[nf][r] = __expf(s[nf][r] - mn); rs += s[nf][r]; }
      rs += __shfl_xor(rs, 1);
      rs += __shfl_xor(rs, 2);
      rs += __shfl_xor(rs, 4);
      rs += __shfl_xor(rs, 8);
      lrow[r] = lrow[r] * fac + rs;
      mrow[r] = mn;
      #pragma unroll
      for (int nf = 0; nf < 4; ++nf) o[nf][r] *= fac;
    }

    // P (C-layout) -> per-wave LDS strip [16][72], re-read as A-fragments.
    // Same-wave RAW through LDS: compiler inserts lgkmcnt wait, no barrier.
    #pragma unroll
    for (int nf = 0; nf < 4; ++nf)
      #pragma unroll
      for (int r = 0; r < 4; ++r)
        pl[w][((l >> 4) * 4 + r) * 72 + nf * 16 + fr] = f2bf(s[nf][r]);

    // O += P @ V
    #pragma unroll
    for (int ks = 0; ks < 2; ++ks){
      const v8s pa = *(const v8s*)(pl[w] + fr * 72 + ks * 32 + fko);
      #pragma unroll
      for (int nf = 0; nf < 4; ++nf){
        const v8s vb = *(const v8s*)(vcur + (nf * 16 + fr) * 72 + ks * 32 + fko);
        o[nf] = __builtin_amdgcn_mfma_f32_16x16x32_bf16(pa, vb, o[nf], 0, 0, 0);
      }
    }
  }

  #pragma unroll
  for (int r = 0; r < 4; ++r){
    const float inv = 1.0f / lrow[r];
    #pragma unroll
    for (int nf = 0; nf < 4; ++nf) o[nf][r] *= inv;
  }
  #pragma unroll
  for (int nf = 0; nf < 4; ++nf)
    #pragma unroll
    for (int r = 0; r < 4; ++r){
      const int row = b * 1024 + qb * 64 + w * 16 + (l >> 4) * 4 + r;
      y[(size_t)row * 1024 + hh * 64 + nf * 16 + fr] = f2bf(o[nf][r]);
    }
}

// ---------------------------------------------------------------- launch
extern "C" void kernel_launch(void* const* d_in, const int* in_sizes, int n_in,
                              void* d_out, int out_size, void* d_ws, size_t ws_size,
                              hipStream_t stream)
{
  const float* seq  = (const float*)d_in[0];
  const float* ln1w = (const float*)d_in[1];
  const float* ln1b = (const float*)d_in[2];
  const float* Wq   = (const float*)d_in[3];
  const float* bq   = (const float*)d_in[4];
  const float* Wk   = (const float*)d_in[5];
  const float* bk   = (const float*)d_in[6];
  const float* Wv   = (const float*)d_in[7];
  const float* bv   = (const float*)d_in[8];
  const float* Wp   = (const float*)d_in[9];
  const float* bp   = (const float*)d_in[10];
  const float* ln2w = (const float*)d_in[11];
  const float* ln2b = (const float*)d_in[12];
  const float* W1   = (const float*)d_in[13];
  const float* b1   = (const float*)d_in[14];
  const float* W2   = (const float*)d_in[15];
  const float* b2   = (const float*)d_in[16];
  const float* lnfw = (const float*)d_in[17];
  const float* lnfb = (const float*)d_in[18];

  char* p = (char*)d_ws;
  auto carve = [&](size_t bytes){
    void* r = (void*)p;
    p += (bytes + 255) & ~(size_t)255;
    return r;
  };
  // all-layer bf16 transposed weights (236 MB total; ws is 512 MiB)
  short* wtQKV = (short*)carve((size_t)8 * 3072 * 1024 * 2);   // [L][3072][1024]
  short* wtP   = (short*)carve((size_t)8 * 1024 * 1024 * 2);   // [L][1024][1024]
  short* wt1   = (short*)carve((size_t)8 * 4096 * 1024 * 2);   // [L][4096][1024]
  short* wt2   = (short*)carve((size_t)8 * 1024 * 4096 * 2);   // [L][1024][4096]
  float* x     = (float*)carve((size_t)2048 * 1024 * 4);
  short* h     = (short*)carve((size_t)2048 * 1024 * 2);
  short* qkv   = (short*)carve((size_t)2048 * 3072 * 2);
  short* y     = (short*)carve((size_t)2048 * 1024 * 2);
  short* hm    = (short*)carve((size_t)2048 * 4096 * 2);

  const size_t S1M = (size_t)1024 * 1024, S3M = (size_t)3072 * 1024,
               S4M = (size_t)4096 * 1024;

  // convert all weights upfront: 6 launches, z = layer
  wconv64<<<dim3(16, 16, 8), 256, 0, stream>>>(Wq, wtQKV,            1024, 1024, S1M, S3M);
  wconv64<<<dim3(16, 16, 8), 256, 0, stream>>>(Wk, wtQKV + S1M,      1024, 1024, S1M, S3M);
  wconv64<<<dim3(16, 16, 8), 256, 0, stream>>>(Wv, wtQKV + 2 * S1M,  1024, 1024, S1M, S3M);
  wconv64<<<dim3(16, 16, 8), 256, 0, stream>>>(Wp, wtP,              1024, 1024, S1M, S1M);
  wconv64<<<dim3(64, 16, 8), 256, 0, stream>>>(W1, wt1,              1024, 4096, S4M, S4M);
  wconv64<<<dim3(16, 64, 8), 256, 0, stream>>>(W2, wt2,              4096, 1024, S4M, S4M);

  for (int l = 0; l < 8; ++l){
    const float* xin = (l == 0) ? seq : x;
    ln_kernel<true><<<2048, 256, 0, stream>>>(xin, ln1w + l * 1024, ln1b + l * 1024, h);
    gemm_kernel<4, 4, 0><<<dim3(24, 16), 256, 0, stream>>>(
        h, wtQKV + l * S3M, qkv, nullptr, bq + l * 1024, bk + l * 1024,
        bv + l * 1024, 2048, 3072, 1024);
    attn_kernel<<<dim3(16, 16, 2), 256, 0, stream>>>(qkv, y);
    gemm_kernel<2, 4, 1><<<dim3(8, 32), 256, 0, stream>>>(
        y, wtP + l * S1M, x, xin, bp + l * 1024, nullptr, nullptr, 2048, 1024, 1024);
    ln_kernel<true><<<2048, 256, 0, stream>>>(x, ln2w + l * 1024, ln2b + l * 1024, h);
    gemm_kernel<4, 4, 2><<<dim3(32, 16), 256, 0, stream>>>(
        h, wt1 + l * S4M, hm, nullptr, b1 + l * 4096, nullptr, nullptr,
        2048, 4096, 1024);
    gemm_kernel<2, 4, 1><<<dim3(8, 32), 256, 0, stream>>>(
        hm, wt2 + l * S4M, x, x, b2 + l * 1024, nullptr, nullptr, 2048, 1024, 4096);
  }
  ln_kernel<false><<<2048, 256, 0, stream>>>(x, lnfw, lnfb, d_out);
}

// Round 3
// 1861.943 us; speedup vs baseline: 1.0225x; 1.0196x over previous
//
#include <hip/hip_runtime.h>
#include <cstdint>

#define DEVI __device__ __forceinline__

typedef short v8s __attribute__((ext_vector_type(8)));
typedef float v4f __attribute__((ext_vector_type(4)));

DEVI short f2bf(float f){
  uint32_t u = __builtin_bit_cast(uint32_t, f);
  u += 0x7FFF + ((u >> 16) & 1);          // round-to-nearest-even
  return (short)(u >> 16);
}
DEVI float bf2f(short s){
  uint32_t u = ((uint32_t)(uint16_t)s) << 16;
  return __builtin_bit_cast(float, u);
}

DEVI void gload16(const void* g, void* l){
  __builtin_amdgcn_global_load_lds(
      (const __attribute__((address_space(1))) unsigned*)g,
      (__attribute__((address_space(3))) unsigned*)l, 16, 0, 0);
}

// ---------------------------------------------------------------- LayerNorm
template<bool BF16OUT>
__global__ __launch_bounds__(256) void ln_kernel(
    const float* __restrict__ x, const float* __restrict__ w,
    const float* __restrict__ b, void* __restrict__ out)
{
  const int row = blockIdx.x;
  const int t = threadIdx.x;
  const float4 v = ((const float4*)(x + (size_t)row * 1024))[t];
  float s  = v.x + v.y + v.z + v.w;
  float s2 = v.x*v.x + v.y*v.y + v.z*v.z + v.w*v.w;
  #pragma unroll
  for (int m = 1; m < 64; m <<= 1){ s += __shfl_xor(s, m); s2 += __shfl_xor(s2, m); }
  __shared__ float ps[4], ps2[4];
  if ((t & 63) == 0){ ps[t >> 6] = s; ps2[t >> 6] = s2; }
  __syncthreads();
  s  = ps[0] + ps[1] + ps[2] + ps[3];
  s2 = ps2[0] + ps2[1] + ps2[2] + ps2[3];
  const float mu = s * (1.f / 1024.f);
  const float rs = rsqrtf(s2 * (1.f / 1024.f) - mu * mu + 1e-5f);
  const float4 wv = ((const float4*)w)[t];
  const float4 bv = ((const float4*)b)[t];
  const float o0 = (v.x - mu) * rs * wv.x + bv.x;
  const float o1 = (v.y - mu) * rs * wv.y + bv.y;
  const float o2 = (v.z - mu) * rs * wv.z + bv.z;
  const float o3 = (v.w - mu) * rs * wv.w + bv.w;
  if (BF16OUT){
    uint2 pk;
    pk.x = (uint16_t)f2bf(o0) | ((uint32_t)(uint16_t)f2bf(o1) << 16);
    pk.y = (uint16_t)f2bf(o2) | ((uint32_t)(uint16_t)f2bf(o3) << 16);
    ((uint2*)out)[(size_t)row * 256 + t] = pk;
  } else {
    ((float4*)out)[(size_t)row * 256 + t] = make_float4(o0, o1, o2, o3);
  }
}

// ---------------- weight fp32[L][K][N] -> bf16[L][N][K], 64x64 tiles, z=layer
__global__ __launch_bounds__(256) void wconv64(
    const float* __restrict__ W, short* __restrict__ Wt,
    int K, int N, size_t in_lstride, size_t out_lstride)
{
  __shared__ float t[64][65];
  const int n0 = blockIdx.x * 64, k0 = blockIdx.y * 64;
  const float* Wl = W + (size_t)blockIdx.z * in_lstride;
  short* Wtl = Wt + (size_t)blockIdx.z * out_lstride;
  const int tid = threadIdx.x;
  const int c4 = (tid & 15) * 4, r = tid >> 4;
  #pragma unroll
  for (int i = 0; i < 4; ++i){
    const float4 v = *(const float4*)(Wl + (size_t)(k0 + r + i*16) * N + n0 + c4);
    t[r + i*16][c4 + 0] = v.x;
    t[r + i*16][c4 + 1] = v.y;
    t[r + i*16][c4 + 2] = v.z;
    t[r + i*16][c4 + 3] = v.w;
  }
  __syncthreads();
  #pragma unroll
  for (int i = 0; i < 4; ++i){
    const int n = r + i*16;
    short4 s;
    s.x = f2bf(t[c4 + 0][n]);
    s.y = f2bf(t[c4 + 1][n]);
    s.z = f2bf(t[c4 + 2][n]);
    s.w = f2bf(t[c4 + 3][n]);
    *(short4*)(Wtl + (size_t)(n0 + n) * K + k0 + c4) = s;
  }
}

// ---------------------------------------------------------------- GEMM
// A: bf16 [M][K] row-major.  Bt: bf16 [N][K] (weight pre-transposed).
// 2-phase double-buffered prefetch: issue next K-tile's global_load_lds into
// the other LDS half BEFORE computing the current tile; single barrier/step
// (its implicit vmcnt(0) drain waits only the residual load latency).
// XCD-aware tile swizzle: contiguous tile chunks per XCD for L2 A-reuse.
// EPI 0: out bf16 = acc + qkv-bias(b0/b1/b2 by col segment of 1024)
// EPI 1: out f32  = resid + acc + b0[col]
// EPI 2: out bf16 = gelu(acc + b0[col])
template<int MF, int NF, int EPI>
__global__ __launch_bounds__(256) void gemm_kernel(
    const short* __restrict__ A, const short* __restrict__ Bt,
    void* __restrict__ out, const float* __restrict__ resid,
    const float* __restrict__ b0, const float* __restrict__ b1,
    const float* __restrict__ b2, int M, int N, int K)
{
  constexpr int BM = 32 * MF, BN = 32 * NF;
  __shared__ __attribute__((aligned(16))) short a_t[2][BM * 64];
  __shared__ __attribute__((aligned(16))) short b_t[2][BN * 64];
  const int tid = threadIdx.x;
  const int l = tid & 63, w = tid >> 6;

  // XCD swizzle (all grids used are divisible by 8): XCD k gets a contiguous
  // tile range; consecutive tiles share the A row-band -> L2-local re-reads.
  const int gx = gridDim.x;
  const int bid = blockIdx.y * gx + blockIdx.x;
  const int cpx = (gx * gridDim.y) >> 3;
  const int swz = (bid & 7) * cpx + (bid >> 3);
  const int m0 = (swz / gx) * BM, n0 = (swz % gx) * BN;

  const int lr = l >> 3;            // staging: row within 8-row group
  const int lc = (l & 7) * 8;       // staging: col start (bf16 elems)
  const int wm = w >> 1, wn = w & 1;
  const int fr = l & 15;            // fragment M-row / N-col index
  const int fko = (l >> 4) * 8;     // fragment K offset (contiguous 8)

  const v4f vz = {0.f, 0.f, 0.f, 0.f};
  v4f acc[MF][NF];
  #pragma unroll
  for (int i = 0; i < MF; ++i)
    #pragma unroll
    for (int j = 0; j < NF; ++j) acc[i][j] = vz;

  auto stage = [&](int buf, int kt){
    #pragma unroll
    for (int j = 0; j < BM / 32; ++j){
      const int rbase = (j * 4 + w) * 8;
      gload16(A + (size_t)(m0 + rbase + lr) * K + kt + lc, a_t[buf] + rbase * 64);
    }
    #pragma unroll
    for (int j = 0; j < BN / 32; ++j){
      const int rbase = (j * 4 + w) * 8;
      gload16(Bt + (size_t)(n0 + rbase + lr) * K + kt + lc, b_t[buf] + rbase * 64);
    }
  };

  const int NT = K >> 6;
  stage(0, 0);
  __syncthreads();                      // drains vmcnt(0): tile 0 resident

  for (int t = 0; t < NT; ++t){
    const int cb = t & 1;
    if (t + 1 < NT) stage(cb ^ 1, (t + 1) << 6);   // prefetch next tile
    #pragma unroll
    for (int ks = 0; ks < 2; ++ks){
      const int co = ks * 32 + fko;
      v8s af[MF], bf[NF];
      #pragma unroll
      for (int mf = 0; mf < MF; ++mf)
        af[mf] = *(const v8s*)(a_t[cb] + (wm * MF * 16 + mf * 16 + fr) * 64 + co);
      #pragma unroll
      for (int nf = 0; nf < NF; ++nf)
        bf[nf] = *(const v8s*)(b_t[cb] + (wn * NF * 16 + nf * 16 + fr) * 64 + co);
      #pragma unroll
      for (int mf = 0; mf < MF; ++mf)
        #pragma unroll
        for (int nf = 0; nf < NF; ++nf)
          acc[mf][nf] = __builtin_amdgcn_mfma_f32_16x16x32_bf16(
              af[mf], bf[nf], acc[mf][nf], 0, 0, 0);
    }
    __syncthreads();                    // next tile resident + cur reads done
  }

  #pragma unroll
  for (int mf = 0; mf < MF; ++mf){
    #pragma unroll
    for (int nf = 0; nf < NF; ++nf){
      const int col = n0 + wn * NF * 16 + nf * 16 + fr;
      float bias;
      if (EPI == 0)
        bias = col < 1024 ? b0[col] : (col < 2048 ? b1[col - 1024] : b2[col - 2048]);
      else
        bias = b0[col];
      #pragma unroll
      for (int r = 0; r < 4; ++r){
        const int row = m0 + wm * MF * 16 + mf * 16 + (l >> 4) * 4 + r;
        const float v = acc[mf][nf][r] + bias;
        if (EPI == 0){
          ((short*)out)[(size_t)row * N + col] = f2bf(v);
        } else if (EPI == 1){
          ((float*)out)[(size_t)row * N + col] =
              resid[(size_t)row * N + col] + v;
        } else {
          const float g = 0.5f * v * (1.0f + erff(v * 0.70710678118f));
          ((short*)out)[(size_t)row * N + col] = f2bf(g);
        }
      }
    }
  }
}

// ---------------------------------------------------------------- Attention
// qkv: bf16 [2048][3072] rows = b*1024+t, cols: q[0:1024) k[1024:2048) v[2048:3072)
// Block-causal TPB=64: query block qb sees key blocks 0..qb fully (no element
// masking). 4 waves, wave w owns q-rows w*16..+15. One barrier per kv-iter:
// vt double-buffered; pl strip is same-wave-only (lgkmcnt dependency).
__global__ __launch_bounds__(256) void attn_kernel(
    const short* __restrict__ qkv, short* __restrict__ y)
{
  const int qb = blockIdx.x, hh = blockIdx.y, b = blockIdx.z;
  const int tid = threadIdx.x, l = tid & 63, w = tid >> 6;
  __shared__ __attribute__((aligned(16))) short vt[2][64 * 72];   // V^T [d][s], padded
  __shared__ __attribute__((aligned(16))) short pl[4][16 * 72];   // per-wave P strip

  const int fr = l & 15;
  const int fko = (l >> 4) * 8;
  const size_t qrow = (size_t)(b * 1024 + qb * 64 + w * 16 + fr) * 3072 + hh * 64 + fko;
  // Q fragment pre-scaled by 1/sqrt(64)=0.125 (power of two: exact in bf16)
  v8s qf0, qf1;
  {
    const v8s q0 = *(const v8s*)(qkv + qrow);
    const v8s q1 = *(const v8s*)(qkv + qrow + 32);
    #pragma unroll
    for (int j = 0; j < 8; ++j){
      qf0[j] = f2bf(bf2f(q0[j]) * 0.125f);
      qf1[j] = f2bf(bf2f(q1[j]) * 0.125f);
    }
  }

  const v4f vz = {0.f, 0.f, 0.f, 0.f};
  v4f o[4] = {vz, vz, vz, vz};
  float mrow[4] = {-1e30f, -1e30f, -1e30f, -1e30f};
  float lrow[4] = {0.f, 0.f, 0.f, 0.f};

  const int vd0 = (tid & 7) * 8, vs0 = (tid >> 3) * 2;
  const short* kbase = qkv + (size_t)(b * 1024) * 3072 + 1024 + hh * 64 + fko;

  for (int kvb = 0; kvb <= qb; ++kvb){
    short* vcur = vt[kvb & 1];
    {
      const short* vsrc = qkv + (size_t)(b * 1024 + kvb * 64 + vs0) * 3072
                          + 2048 + hh * 64 + vd0;
      const v8s r0 = *(const v8s*)vsrc;
      const v8s r1 = *(const v8s*)(vsrc + 3072);
      #pragma unroll
      for (int j = 0; j < 8; ++j){
        const uint32_t pk = (uint16_t)r0[j] | ((uint32_t)(uint16_t)r1[j] << 16);
        *(uint32_t*)(vcur + (vd0 + j) * 72 + vs0) = pk;
      }
    }
    __syncthreads();

    // S = Q K^T (16 q-rows x 64 keys per wave), K fragments direct from global
    v4f s[4] = {vz, vz, vz, vz};
    #pragma unroll
    for (int nf = 0; nf < 4; ++nf){
      const short* kp = kbase + (size_t)(kvb * 64 + nf * 16 + fr) * 3072;
      const v8s kb0 = *(const v8s*)kp;
      const v8s kb1 = *(const v8s*)(kp + 32);
      s[nf] = __builtin_amdgcn_mfma_f32_16x16x32_bf16(qf0, kb0, s[nf], 0, 0, 0);
      s[nf] = __builtin_amdgcn_mfma_f32_16x16x32_bf16(qf1, kb1, s[nf], 0, 0, 0);
    }

    // online softmax: lane's 4 rows are t_local=(l>>4)*4+r; row-reduce over
    // the 16 lanes sharing l>>4 (xor 1,2,4,8)
    #pragma unroll
    for (int r = 0; r < 4; ++r){
      float mx = fmaxf(fmaxf(s[0][r], s[1][r]), fmaxf(s[2][r], s[3][r]));
      mx = fmaxf(mx, __shfl_xor(mx, 1));
      mx = fmaxf(mx, __shfl_xor(mx, 2));
      mx = fmaxf(mx, __shfl_xor(mx, 4));
      mx = fmaxf(mx, __shfl_xor(mx, 8));
      const float mn = fmaxf(mrow[r], mx);
      const float fac = __expf(mrow[r] - mn);
      float rs = 0.f;
      #pragma unroll
      for (int nf = 0; nf < 4; ++nf){ s[nf][r] = __expf(s[nf][r] - mn); rs += s[nf][r]; }
      rs += __shfl_xor(rs, 1);
      rs += __shfl_xor(rs, 2);
      rs += __shfl_xor(rs, 4);
      rs += __shfl_xor(rs, 8);
      lrow[r] = lrow[r] * fac + rs;
      mrow[r] = mn;
      #pragma unroll
      for (int nf = 0; nf < 4; ++nf) o[nf][r] *= fac;
    }

    // P (C-layout) -> per-wave LDS strip [16][72], re-read as A-fragments.
    #pragma unroll
    for (int nf = 0; nf < 4; ++nf)
      #pragma unroll
      for (int r = 0; r < 4; ++r)
        pl[w][((l >> 4) * 4 + r) * 72 + nf * 16 + fr] = f2bf(s[nf][r]);

    // O += P @ V
    #pragma unroll
    for (int ks = 0; ks < 2; ++ks){
      const v8s pa = *(const v8s*)(pl[w] + fr * 72 + ks * 32 + fko);
      #pragma unroll
      for (int nf = 0; nf < 4; ++nf){
        const v8s vb = *(const v8s*)(vcur + (nf * 16 + fr) * 72 + ks * 32 + fko);
        o[nf] = __builtin_amdgcn_mfma_f32_16x16x32_bf16(pa, vb, o[nf], 0, 0, 0);
      }
    }
  }

  #pragma unroll
  for (int r = 0; r < 4; ++r){
    const float inv = 1.0f / lrow[r];
    #pragma unroll
    for (int nf = 0; nf < 4; ++nf) o[nf][r] *= inv;
  }
  #pragma unroll
  for (int nf = 0; nf < 4; ++nf)
    #pragma unroll
    for (int r = 0; r < 4; ++r){
      const int row = b * 1024 + qb * 64 + w * 16 + (l >> 4) * 4 + r;
      y[(size_t)row * 1024 + hh * 64 + nf * 16 + fr] = f2bf(o[nf][r]);
    }
}

// ---------------------------------------------------------------- launch
extern "C" void kernel_launch(void* const* d_in, const int* in_sizes, int n_in,
                              void* d_out, int out_size, void* d_ws, size_t ws_size,
                              hipStream_t stream)
{
  const float* seq  = (const float*)d_in[0];
  const float* ln1w = (const float*)d_in[1];
  const float* ln1b = (const float*)d_in[2];
  const float* Wq   = (const float*)d_in[3];
  const float* bq   = (const float*)d_in[4];
  const float* Wk   = (const float*)d_in[5];
  const float* bk   = (const float*)d_in[6];
  const float* Wv   = (const float*)d_in[7];
  const float* bv   = (const float*)d_in[8];
  const float* Wp   = (const float*)d_in[9];
  const float* bp   = (const float*)d_in[10];
  const float* ln2w = (const float*)d_in[11];
  const float* ln2b = (const float*)d_in[12];
  const float* W1   = (const float*)d_in[13];
  const float* b1   = (const float*)d_in[14];
  const float* W2   = (const float*)d_in[15];
  const float* b2   = (const float*)d_in[16];
  const float* lnfw = (const float*)d_in[17];
  const float* lnfb = (const float*)d_in[18];

  char* p = (char*)d_ws;
  auto carve = [&](size_t bytes){
    void* r = (void*)p;
    p += (bytes + 255) & ~(size_t)255;
    return r;
  };
  // all-layer bf16 transposed weights (236 MB total; ws is 512 MiB)
  short* wtQKV = (short*)carve((size_t)8 * 3072 * 1024 * 2);   // [L][3072][1024]
  short* wtP   = (short*)carve((size_t)8 * 1024 * 1024 * 2);   // [L][1024][1024]
  short* wt1   = (short*)carve((size_t)8 * 4096 * 1024 * 2);   // [L][4096][1024]
  short* wt2   = (short*)carve((size_t)8 * 1024 * 4096 * 2);   // [L][1024][4096]
  float* x     = (float*)carve((size_t)2048 * 1024 * 4);
  short* h     = (short*)carve((size_t)2048 * 1024 * 2);
  short* qkv   = (short*)carve((size_t)2048 * 3072 * 2);
  short* y     = (short*)carve((size_t)2048 * 1024 * 2);
  short* hm    = (short*)carve((size_t)2048 * 4096 * 2);

  const size_t S1M = (size_t)1024 * 1024, S3M = (size_t)3072 * 1024,
               S4M = (size_t)4096 * 1024;

  // convert all weights upfront: 6 launches, z = layer
  wconv64<<<dim3(16, 16, 8), 256, 0, stream>>>(Wq, wtQKV,            1024, 1024, S1M, S3M);
  wconv64<<<dim3(16, 16, 8), 256, 0, stream>>>(Wk, wtQKV + S1M,      1024, 1024, S1M, S3M);
  wconv64<<<dim3(16, 16, 8), 256, 0, stream>>>(Wv, wtQKV + 2 * S1M,  1024, 1024, S1M, S3M);
  wconv64<<<dim3(16, 16, 8), 256, 0, stream>>>(Wp, wtP,              1024, 1024, S1M, S1M);
  wconv64<<<dim3(64, 16, 8), 256, 0, stream>>>(W1, wt1,              1024, 4096, S4M, S4M);
  wconv64<<<dim3(16, 64, 8), 256, 0, stream>>>(W2, wt2,              4096, 1024, S4M, S4M);

  for (int l = 0; l < 8; ++l){
    const float* xin = (l == 0) ? seq : x;
    ln_kernel<true><<<2048, 256, 0, stream>>>(xin, ln1w + l * 1024, ln1b + l * 1024, h);
    gemm_kernel<4, 4, 0><<<dim3(24, 16), 256, 0, stream>>>(
        h, wtQKV + l * S3M, qkv, nullptr, bq + l * 1024, bk + l * 1024,
        bv + l * 1024, 2048, 3072, 1024);
    attn_kernel<<<dim3(16, 16, 2), 256, 0, stream>>>(qkv, y);
    gemm_kernel<2, 4, 1><<<dim3(8, 32), 256, 0, stream>>>(
        y, wtP + l * S1M, x, xin, bp + l * 1024, nullptr, nullptr, 2048, 1024, 1024);
    ln_kernel<true><<<2048, 256, 0, stream>>>(x, ln2w + l * 1024, ln2b + l * 1024, h);
    gemm_kernel<4, 4, 2><<<dim3(32, 16), 256, 0, stream>>>(
        h, wt1 + l * S4M, hm, nullptr, b1 + l * 4096, nullptr, nullptr,
        2048, 4096, 1024);
    gemm_kernel<2, 4, 1><<<dim3(8, 32), 256, 0, stream>>>(
        hm, wt2 + l * S4M, x, x, b2 + l * 1024, nullptr, nullptr, 2048, 1024, 4096);
  }
  ln_kernel<false><<<2048, 256, 0, stream>>>(x, lnfw, lnfb, d_out);
}

// Round 4
// 1790.764 us; speedup vs baseline: 1.0631x; 1.0397x over previous
//
#include <hip/hip_runtime.h>
#include <cstdint>

#define DEVI __device__ __forceinline__

typedef short v8s __attribute__((ext_vector_type(8)));
typedef float v4f __attribute__((ext_vector_type(4)));

DEVI short f2bf(float f){
  uint32_t u = __builtin_bit_cast(uint32_t, f);
  u += 0x7FFF + ((u >> 16) & 1);          // round-to-nearest-even
  return (short)(u >> 16);
}
DEVI float bf2f(short s){
  uint32_t u = ((uint32_t)(uint16_t)s) << 16;
  return __builtin_bit_cast(float, u);
}

DEVI void gload16(const void* g, void* l){
  __builtin_amdgcn_global_load_lds(
      (const __attribute__((address_space(1))) unsigned*)g,
      (__attribute__((address_space(3))) unsigned*)l, 16, 0, 0);
}

template<int N> DEVI void waitvm(){
  if constexpr (N == 0)      asm volatile("s_waitcnt vmcnt(0)" ::: "memory");
  else if constexpr (N == 6) asm volatile("s_waitcnt vmcnt(6)" ::: "memory");
  else if constexpr (N == 8) asm volatile("s_waitcnt vmcnt(8)" ::: "memory");
  else static_assert(N == 0 || N == 6 || N == 8, "add literal");
}

// ---------------------------------------------------------------- LayerNorm
template<bool BF16OUT>
__global__ __launch_bounds__(256) void ln_kernel(
    const float* __restrict__ x, const float* __restrict__ w,
    const float* __restrict__ b, void* __restrict__ out)
{
  const int row = blockIdx.x;
  const int t = threadIdx.x;
  const float4 v = ((const float4*)(x + (size_t)row * 1024))[t];
  float s  = v.x + v.y + v.z + v.w;
  float s2 = v.x*v.x + v.y*v.y + v.z*v.z + v.w*v.w;
  #pragma unroll
  for (int m = 1; m < 64; m <<= 1){ s += __shfl_xor(s, m); s2 += __shfl_xor(s2, m); }
  __shared__ float ps[4], ps2[4];
  if ((t & 63) == 0){ ps[t >> 6] = s; ps2[t >> 6] = s2; }
  __syncthreads();
  s  = ps[0] + ps[1] + ps[2] + ps[3];
  s2 = ps2[0] + ps2[1] + ps2[2] + ps2[3];
  const float mu = s * (1.f / 1024.f);
  const float rs = rsqrtf(s2 * (1.f / 1024.f) - mu * mu + 1e-5f);
  const float4 wv = ((const float4*)w)[t];
  const float4 bv = ((const float4*)b)[t];
  const float o0 = (v.x - mu) * rs * wv.x + bv.x;
  const float o1 = (v.y - mu) * rs * wv.y + bv.y;
  const float o2 = (v.z - mu) * rs * wv.z + bv.z;
  const float o3 = (v.w - mu) * rs * wv.w + bv.w;
  if (BF16OUT){
    uint2 pk;
    pk.x = (uint16_t)f2bf(o0) | ((uint32_t)(uint16_t)f2bf(o1) << 16);
    pk.y = (uint16_t)f2bf(o2) | ((uint32_t)(uint16_t)f2bf(o3) << 16);
    ((uint2*)out)[(size_t)row * 256 + t] = pk;
  } else {
    ((float4*)out)[(size_t)row * 256 + t] = make_float4(o0, o1, o2, o3);
  }
}

// ---------------- weight fp32[L][K][N] -> bf16[L][N][K], 64x64 tiles, z=layer
__global__ __launch_bounds__(256) void wconv64(
    const float* __restrict__ W, short* __restrict__ Wt,
    int K, int N, size_t in_lstride, size_t out_lstride)
{
  __shared__ float t[64][65];
  const int n0 = blockIdx.x * 64, k0 = blockIdx.y * 64;
  const float* Wl = W + (size_t)blockIdx.z * in_lstride;
  short* Wtl = Wt + (size_t)blockIdx.z * out_lstride;
  const int tid = threadIdx.x;
  const int c4 = (tid & 15) * 4, r = tid >> 4;
  #pragma unroll
  for (int i = 0; i < 4; ++i){
    const float4 v = *(const float4*)(Wl + (size_t)(k0 + r + i*16) * N + n0 + c4);
    t[r + i*16][c4 + 0] = v.x;
    t[r + i*16][c4 + 1] = v.y;
    t[r + i*16][c4 + 2] = v.z;
    t[r + i*16][c4 + 3] = v.w;
  }
  __syncthreads();
  #pragma unroll
  for (int i = 0; i < 4; ++i){
    const int n = r + i*16;
    short4 s;
    s.x = f2bf(t[c4 + 0][n]);
    s.y = f2bf(t[c4 + 1][n]);
    s.z = f2bf(t[c4 + 2][n]);
    s.w = f2bf(t[c4 + 3][n]);
    *(short4*)(Wtl + (size_t)(n0 + n) * K + k0 + c4) = s;
  }
}

// ---------------------------------------------------------------- GEMM
// A: bf16 [M][K] row-major.  Bt: bf16 [N][K] (weight pre-transposed).
// Pipeline: 3 LDS buffers, 2-tile-deep global_load_lds prefetch, counted
// s_waitcnt vmcnt(L) per iter (L = loads/stage = MF+NF; vmcnt(0) only on the
// last tile) + raw s_barrier -- no full drain in the main loop (T4).
// LDS XOR-swizzle (T2, rule #21): gload_lds writes linearly; the per-lane
// GLOBAL source column is pre-XORed by (row&7)<<4 bytes and the fragment
// ds_read applies the same XOR -> 16-way bank conflict becomes 2-way (free).
// XCD-aware tile swizzle (T1) for L2 locality.
// EPI 0: out bf16 = acc + qkv-bias(b0/b1/b2 by col segment of 1024)
// EPI 1: out f32  = resid + acc + b0[col]
// EPI 2: out bf16 = gelu(acc + b0[col])
template<int MF, int NF, int EPI>
__global__ __launch_bounds__(256) void gemm_kernel(
    const short* __restrict__ A, const short* __restrict__ Bt,
    void* __restrict__ out, const float* __restrict__ resid,
    const float* __restrict__ b0, const float* __restrict__ b1,
    const float* __restrict__ b2, int M, int N, int K)
{
  constexpr int BM = 32 * MF, BN = 32 * NF;
  constexpr int L = MF + NF;              // gload16 per wave per stage
  __shared__ __attribute__((aligned(16))) short a_t[3][BM * 64];
  __shared__ __attribute__((aligned(16))) short b_t[3][BN * 64];
  const int tid = threadIdx.x;
  const int l = tid & 63, w = tid >> 6;

  // XCD swizzle (all grids used are divisible by 8)
  const int gx = gridDim.x;
  const int bid = blockIdx.y * gx + blockIdx.x;
  const int cpx = (gx * gridDim.y) >> 3;
  const int swz = (bid & 7) * cpx + (bid >> 3);
  const int m0 = (swz / gx) * BM, n0 = (swz % gx) * BN;

  const int lr = l >> 3;                  // staging: row within 8-row group
  const int scol = ((l & 7) * 16) ^ (lr << 4);   // swizzled source byte col
  const int wm = w >> 1, wn = w & 1;
  const int fr = l & 15;                  // fragment M-row / N-col index
  const int rxor = (fr & 7) << 4;         // read-side XOR (bytes)

  const v4f vz = {0.f, 0.f, 0.f, 0.f};
  v4f acc[MF][NF];
  #pragma unroll
  for (int i = 0; i < MF; ++i)
    #pragma unroll
    for (int j = 0; j < NF; ++j) acc[i][j] = vz;

  const char* Ab = (const char*)A;
  const char* Bb = (const char*)Bt;
  auto stage = [&](int buf, int kt){
    #pragma unroll
    for (int j = 0; j < BM / 32; ++j){
      const int rbase = (j * 4 + w) * 8;
      gload16(Ab + ((size_t)(m0 + rbase + lr) * K + kt) * 2 + scol,
              a_t[buf] + rbase * 64);
    }
    #pragma unroll
    for (int j = 0; j < BN / 32; ++j){
      const int rbase = (j * 4 + w) * 8;
      gload16(Bb + ((size_t)(n0 + rbase + lr) * K + kt) * 2 + scol,
              b_t[buf] + rbase * 64);
    }
  };

  const int NT = K >> 6;
  stage(0, 0);
  stage(1, 64);
  int cb = 0, sb = 2;
  for (int t = 0; t < NT; ++t){
    if (t + 1 < NT) waitvm<L>(); else waitvm<0>();
    __builtin_amdgcn_s_barrier();
    const char* ab = (const char*)a_t[cb];
    const char* bb = (const char*)b_t[cb];
    #pragma unroll
    for (int ks = 0; ks < 2; ++ks){
      const int co = ks * 64 + (l >> 4) * 16;   // byte col within row
      v8s af[MF], bf[NF];
      #pragma unroll
      for (int mf = 0; mf < MF; ++mf)
        af[mf] = *(const v8s*)(ab + (wm * MF * 16 + mf * 16 + fr) * 128 + (co ^ rxor));
      #pragma unroll
      for (int nf = 0; nf < NF; ++nf)
        bf[nf] = *(const v8s*)(bb + (wn * NF * 16 + nf * 16 + fr) * 128 + (co ^ rxor));
      #pragma unroll
      for (int mf = 0; mf < MF; ++mf)
        #pragma unroll
        for (int nf = 0; nf < NF; ++nf)
          acc[mf][nf] = __builtin_amdgcn_mfma_f32_16x16x32_bf16(
              af[mf], bf[nf], acc[mf][nf], 0, 0, 0);
    }
    if (t + 2 < NT) stage(sb, (t + 2) << 6);
    cb = cb == 2 ? 0 : cb + 1;
    sb = sb == 2 ? 0 : sb + 1;
  }

  #pragma unroll
  for (int mf = 0; mf < MF; ++mf){
    #pragma unroll
    for (int nf = 0; nf < NF; ++nf){
      const int col = n0 + wn * NF * 16 + nf * 16 + fr;
      float bias;
      if (EPI == 0)
        bias = col < 1024 ? b0[col] : (col < 2048 ? b1[col - 1024] : b2[col - 2048]);
      else
        bias = b0[col];
      #pragma unroll
      for (int r = 0; r < 4; ++r){
        const int row = m0 + wm * MF * 16 + mf * 16 + (l >> 4) * 4 + r;
        const float v = acc[mf][nf][r] + bias;
        if (EPI == 0){
          ((short*)out)[(size_t)row * N + col] = f2bf(v);
        } else if (EPI == 1){
          ((float*)out)[(size_t)row * N + col] =
              resid[(size_t)row * N + col] + v;
        } else {
          const float g = 0.5f * v * (1.0f + erff(v * 0.70710678118f));
          ((short*)out)[(size_t)row * N + col] = f2bf(g);
        }
      }
    }
  }
}

// ---------------------------------------------------------------- Attention
// qkv: bf16 [2048][3072] rows = b*1024+t, cols: q[0:1024) k[1024:2048) v[2048:3072)
// Block-causal TPB=64: query block qb sees key blocks 0..qb fully (no element
// masking). 4 waves, wave w owns q-rows w*16..+15. One barrier per kv-iter:
// vt double-buffered; pl strip is same-wave-only (lgkmcnt dependency).
__global__ __launch_bounds__(256) void attn_kernel(
    const short* __restrict__ qkv, short* __restrict__ y)
{
  const int qb = blockIdx.x, hh = blockIdx.y, b = blockIdx.z;
  const int tid = threadIdx.x, l = tid & 63, w = tid >> 6;
  __shared__ __attribute__((aligned(16))) short vt[2][64 * 72];   // V^T [d][s], padded
  __shared__ __attribute__((aligned(16))) short pl[4][16 * 72];   // per-wave P strip

  const int fr = l & 15;
  const int fko = (l >> 4) * 8;
  const size_t qrow = (size_t)(b * 1024 + qb * 64 + w * 16 + fr) * 3072 + hh * 64 + fko;
  // Q fragment pre-scaled by 1/sqrt(64)=0.125 (power of two: exact in bf16)
  v8s qf0, qf1;
  {
    const v8s q0 = *(const v8s*)(qkv + qrow);
    const v8s q1 = *(const v8s*)(qkv + qrow + 32);
    #pragma unroll
    for (int j = 0; j < 8; ++j){
      qf0[j] = f2bf(bf2f(q0[j]) * 0.125f);
      qf1[j] = f2bf(bf2f(q1[j]) * 0.125f);
    }
  }

  const v4f vz = {0.f, 0.f, 0.f, 0.f};
  v4f o[4] = {vz, vz, vz, vz};
  float mrow[4] = {-1e30f, -1e30f, -1e30f, -1e30f};
  float lrow[4] = {0.f, 0.f, 0.f, 0.f};

  const int vd0 = (tid & 7) * 8, vs0 = (tid >> 3) * 2;
  const short* kbase = qkv + (size_t)(b * 1024) * 3072 + 1024 + hh * 64 + fko;

  for (int kvb = 0; kvb <= qb; ++kvb){
    short* vcur = vt[kvb & 1];
    {
      const short* vsrc = qkv + (size_t)(b * 1024 + kvb * 64 + vs0) * 3072
                          + 2048 + hh * 64 + vd0;
      const v8s r0 = *(const v8s*)vsrc;
      const v8s r1 = *(const v8s*)(vsrc + 3072);
      #pragma unroll
      for (int j = 0; j < 8; ++j){
        const uint32_t pk = (uint16_t)r0[j] | ((uint32_t)(uint16_t)r1[j] << 16);
        *(uint32_t*)(vcur + (vd0 + j) * 72 + vs0) = pk;
      }
    }
    __syncthreads();

    // S = Q K^T (16 q-rows x 64 keys per wave), K fragments direct from global
    v4f s[4] = {vz, vz, vz, vz};
    #pragma unroll
    for (int nf = 0; nf < 4; ++nf){
      const short* kp = kbase + (size_t)(kvb * 64 + nf * 16 + fr) * 3072;
      const v8s kb0 = *(const v8s*)kp;
      const v8s kb1 = *(const v8s*)(kp + 32);
      s[nf] = __builtin_amdgcn_mfma_f32_16x16x32_bf16(qf0, kb0, s[nf], 0, 0, 0);
      s[nf] = __builtin_amdgcn_mfma_f32_16x16x32_bf16(qf1, kb1, s[nf], 0, 0, 0);
    }

    // online softmax: lane's 4 rows are t_local=(l>>4)*4+r; row-reduce over
    // the 16 lanes sharing l>>4 (xor 1,2,4,8)
    #pragma unroll
    for (int r = 0; r < 4; ++r){
      float mx = fmaxf(fmaxf(s[0][r], s[1][r]), fmaxf(s[2][r], s[3][r]));
      mx = fmaxf(mx, __shfl_xor(mx, 1));
      mx = fmaxf(mx, __shfl_xor(mx, 2));
      mx = fmaxf(mx, __shfl_xor(mx, 4));
      mx = fmaxf(mx, __shfl_xor(mx, 8));
      const float mn = fmaxf(mrow[r], mx);
      const float fac = __expf(mrow[r] - mn);
      float rs = 0.f;
      #pragma unroll
      for (int nf = 0; nf < 4; ++nf){ s[nf][r] = __expf(s[nf][r] - mn); rs += s[nf][r]; }
      rs += __shfl_xor(rs, 1);
      rs += __shfl_xor(rs, 2);
      rs += __shfl_xor(rs, 4);
      rs += __shfl_xor(rs, 8);
      lrow[r] = lrow[r] * fac + rs;
      mrow[r] = mn;
      #pragma unroll
      for (int nf = 0; nf < 4; ++nf) o[nf][r] *= fac;
    }

    // P (C-layout) -> per-wave LDS strip [16][72], re-read as A-fragments.
    #pragma unroll
    for (int nf = 0; nf < 4; ++nf)
      #pragma unroll
      for (int r = 0; r < 4; ++r)
        pl[w][((l >> 4) * 4 + r) * 72 + nf * 16 + fr] = f2bf(s[nf][r]);

    // O += P @ V
    #pragma unroll
    for (int ks = 0; ks < 2; ++ks){
      const v8s pa = *(const v8s*)(pl[w] + fr * 72 + ks * 32 + fko);
      #pragma unroll
      for (int nf = 0; nf < 4; ++nf){
        const v8s vb = *(const v8s*)(vcur + (nf * 16 + fr) * 72 + ks * 32 + fko);
        o[nf] = __builtin_amdgcn_mfma_f32_16x16x32_bf16(pa, vb, o[nf], 0, 0, 0);
      }
    }
  }

  #pragma unroll
  for (int r = 0; r < 4; ++r){
    const float inv = 1.0f / lrow[r];
    #pragma unroll
    for (int nf = 0; nf < 4; ++nf) o[nf][r] *= inv;
  }
  #pragma unroll
  for (int nf = 0; nf < 4; ++nf)
    #pragma unroll
    for (int r = 0; r < 4; ++r){
      const int row = b * 1024 + qb * 64 + w * 16 + (l >> 4) * 4 + r;
      y[(size_t)row * 1024 + hh * 64 + nf * 16 + fr] = f2bf(o[nf][r]);
    }
}

// ---------------------------------------------------------------- launch
extern "C" void kernel_launch(void* const* d_in, const int* in_sizes, int n_in,
                              void* d_out, int out_size, void* d_ws, size_t ws_size,
                              hipStream_t stream)
{
  const float* seq  = (const float*)d_in[0];
  const float* ln1w = (const float*)d_in[1];
  const float* ln1b = (const float*)d_in[2];
  const float* Wq   = (const float*)d_in[3];
  const float* bq   = (const float*)d_in[4];
  const float* Wk   = (const float*)d_in[5];
  const float* bk   = (const float*)d_in[6];
  const float* Wv   = (const float*)d_in[7];
  const float* bv   = (const float*)d_in[8];
  const float* Wp   = (const float*)d_in[9];
  const float* bp   = (const float*)d_in[10];
  const float* ln2w = (const float*)d_in[11];
  const float* ln2b = (const float*)d_in[12];
  const float* W1   = (const float*)d_in[13];
  const float* b1   = (const float*)d_in[14];
  const float* W2   = (const float*)d_in[15];
  const float* b2   = (const float*)d_in[16];
  const float* lnfw = (const float*)d_in[17];
  const float* lnfb = (const float*)d_in[18];

  char* p = (char*)d_ws;
  auto carve = [&](size_t bytes){
    void* r = (void*)p;
    p += (bytes + 255) & ~(size_t)255;
    return r;
  };
  // all-layer bf16 transposed weights (236 MB total; ws is 512 MiB)
  short* wtQKV = (short*)carve((size_t)8 * 3072 * 1024 * 2);   // [L][3072][1024]
  short* wtP   = (short*)carve((size_t)8 * 1024 * 1024 * 2);   // [L][1024][1024]
  short* wt1   = (short*)carve((size_t)8 * 4096 * 1024 * 2);   // [L][4096][1024]
  short* wt2   = (short*)carve((size_t)8 * 1024 * 4096 * 2);   // [L][1024][4096]
  float* x     = (float*)carve((size_t)2048 * 1024 * 4);
  short* h     = (short*)carve((size_t)2048 * 1024 * 2);
  short* qkv   = (short*)carve((size_t)2048 * 3072 * 2);
  short* y     = (short*)carve((size_t)2048 * 1024 * 2);
  short* hm    = (short*)carve((size_t)2048 * 4096 * 2);

  const size_t S1M = (size_t)1024 * 1024, S3M = (size_t)3072 * 1024,
               S4M = (size_t)4096 * 1024;

  // convert all weights upfront: 6 launches, z = layer
  wconv64<<<dim3(16, 16, 8), 256, 0, stream>>>(Wq, wtQKV,            1024, 1024, S1M, S3M);
  wconv64<<<dim3(16, 16, 8), 256, 0, stream>>>(Wk, wtQKV + S1M,      1024, 1024, S1M, S3M);
  wconv64<<<dim3(16, 16, 8), 256, 0, stream>>>(Wv, wtQKV + 2 * S1M,  1024, 1024, S1M, S3M);
  wconv64<<<dim3(16, 16, 8), 256, 0, stream>>>(Wp, wtP,              1024, 1024, S1M, S1M);
  wconv64<<<dim3(64, 16, 8), 256, 0, stream>>>(W1, wt1,              1024, 4096, S4M, S4M);
  wconv64<<<dim3(16, 64, 8), 256, 0, stream>>>(W2, wt2,              4096, 1024, S4M, S4M);

  for (int l = 0; l < 8; ++l){
    const float* xin = (l == 0) ? seq : x;
    ln_kernel<true><<<2048, 256, 0, stream>>>(xin, ln1w + l * 1024, ln1b + l * 1024, h);
    gemm_kernel<4, 4, 0><<<dim3(24, 16), 256, 0, stream>>>(
        h, wtQKV + l * S3M, qkv, nullptr, bq + l * 1024, bk + l * 1024,
        bv + l * 1024, 2048, 3072, 1024);
    attn_kernel<<<dim3(16, 16, 2), 256, 0, stream>>>(qkv, y);
    gemm_kernel<2, 4, 1><<<dim3(8, 32), 256, 0, stream>>>(
        y, wtP + l * S1M, x, xin, bp + l * 1024, nullptr, nullptr, 2048, 1024, 1024);
    ln_kernel<true><<<2048, 256, 0, stream>>>(x, ln2w + l * 1024, ln2b + l * 1024, h);
    gemm_kernel<4, 4, 2><<<dim3(32, 16), 256, 0, stream>>>(
        h, wt1 + l * S4M, hm, nullptr, b1 + l * 4096, nullptr, nullptr,
        2048, 4096, 1024);
    gemm_kernel<2, 4, 1><<<dim3(8, 32), 256, 0, stream>>>(
        hm, wt2 + l * S4M, x, x, b2 + l * 1024, nullptr, nullptr, 2048, 1024, 4096);
  }
  ln_kernel<false><<<2048, 256, 0, stream>>>(x, lnfw, lnfb, d_out);
}

// Round 5
// 1411.541 us; speedup vs baseline: 1.3487x; 1.2687x over previous
//
#include <hip/hip_runtime.h>
#include <cstdint>

#define DEVI __device__ __forceinline__

typedef short v8s __attribute__((ext_vector_type(8)));
typedef float v4f __attribute__((ext_vector_type(4)));

DEVI short f2bf(float f){
  uint32_t u = __builtin_bit_cast(uint32_t, f);
  u += 0x7FFF + ((u >> 16) & 1);          // round-to-nearest-even
  return (short)(u >> 16);
}
DEVI float bf2f(short s){
  uint32_t u = ((uint32_t)(uint16_t)s) << 16;
  return __builtin_bit_cast(float, u);
}

DEVI void gload16(const void* g, void* l){
  __builtin_amdgcn_global_load_lds(
      (const __attribute__((address_space(1))) unsigned*)g,
      (__attribute__((address_space(3))) unsigned*)l, 16, 0, 0);
}

// ---------------------------------------------------------------- LayerNorm
// (only used standalone for the very first ln1 on seq)
__global__ __launch_bounds__(256) void ln_kernel(
    const float* __restrict__ x, const float* __restrict__ w,
    const float* __restrict__ b, void* __restrict__ out)
{
  const int row = blockIdx.x;
  const int t = threadIdx.x;
  const float4 v = ((const float4*)(x + (size_t)row * 1024))[t];
  float s  = v.x + v.y + v.z + v.w;
  float s2 = v.x*v.x + v.y*v.y + v.z*v.z + v.w*v.w;
  #pragma unroll
  for (int m = 1; m < 64; m <<= 1){ s += __shfl_xor(s, m); s2 += __shfl_xor(s2, m); }
  __shared__ float ps[4], ps2[4];
  if ((t & 63) == 0){ ps[t >> 6] = s; ps2[t >> 6] = s2; }
  __syncthreads();
  s  = ps[0] + ps[1] + ps[2] + ps[3];
  s2 = ps2[0] + ps2[1] + ps2[2] + ps2[3];
  const float mu = s * (1.f / 1024.f);
  const float rs = rsqrtf(s2 * (1.f / 1024.f) - mu * mu + 1e-5f);
  const float4 wv = ((const float4*)w)[t];
  const float4 bv = ((const float4*)b)[t];
  uint2 pk;
  pk.x = (uint16_t)f2bf((v.x - mu) * rs * wv.x + bv.x)
       | ((uint32_t)(uint16_t)f2bf((v.y - mu) * rs * wv.y + bv.y) << 16);
  pk.y = (uint16_t)f2bf((v.z - mu) * rs * wv.z + bv.z)
       | ((uint32_t)(uint16_t)f2bf((v.w - mu) * rs * wv.w + bv.w) << 16);
  ((uint2*)out)[(size_t)row * 256 + t] = pk;
}

// ------------- split-K reduce + residual + bias, fused with LayerNorm.
// x = resid + bias + sum_s part[s]; then LN(x) -> h (bf16) or d_out (fp32).
template<int S, bool FIN>
__global__ __launch_bounds__(256) void reduce_ln(
    const float* __restrict__ part, const float* __restrict__ resid,
    const float* __restrict__ bias, float* __restrict__ xout,
    const float* __restrict__ lw, const float* __restrict__ lb,
    void* __restrict__ hout)
{
  const int row = blockIdx.x;
  const int t = threadIdx.x;
  float4 v = ((const float4*)(resid + (size_t)row * 1024))[t];
  const float4 bz = ((const float4*)bias)[t];
  v.x += bz.x; v.y += bz.y; v.z += bz.z; v.w += bz.w;
  #pragma unroll
  for (int s = 0; s < S; ++s){
    const float4 pv = ((const float4*)(part + ((size_t)s * 2048 + row) * 1024))[t];
    v.x += pv.x; v.y += pv.y; v.z += pv.z; v.w += pv.w;
  }
  ((float4*)(xout + (size_t)row * 1024))[t] = v;
  float s  = v.x + v.y + v.z + v.w;
  float s2 = v.x*v.x + v.y*v.y + v.z*v.z + v.w*v.w;
  #pragma unroll
  for (int m = 1; m < 64; m <<= 1){ s += __shfl_xor(s, m); s2 += __shfl_xor(s2, m); }
  __shared__ float ps[4], ps2[4];
  if ((t & 63) == 0){ ps[t >> 6] = s; ps2[t >> 6] = s2; }
  __syncthreads();
  s  = ps[0] + ps[1] + ps[2] + ps[3];
  s2 = ps2[0] + ps2[1] + ps2[2] + ps2[3];
  const float mu = s * (1.f / 1024.f);
  const float rs = rsqrtf(s2 * (1.f / 1024.f) - mu * mu + 1e-5f);
  const float4 wv = ((const float4*)lw)[t];
  const float4 bv = ((const float4*)lb)[t];
  const float o0 = (v.x - mu) * rs * wv.x + bv.x;
  const float o1 = (v.y - mu) * rs * wv.y + bv.y;
  const float o2 = (v.z - mu) * rs * wv.z + bv.z;
  const float o3 = (v.w - mu) * rs * wv.w + bv.w;
  if (FIN){
    ((float4*)hout)[(size_t)row * 256 + t] = make_float4(o0, o1, o2, o3);
  } else {
    uint2 pk;
    pk.x = (uint16_t)f2bf(o0) | ((uint32_t)(uint16_t)f2bf(o1) << 16);
    pk.y = (uint16_t)f2bf(o2) | ((uint32_t)(uint16_t)f2bf(o3) << 16);
    ((uint2*)hout)[(size_t)row * 256 + t] = pk;
  }
}

// ---------------- weight fp32[L][K][N] -> bf16[L][N][K], 64x64 tiles, z=layer
__global__ __launch_bounds__(256) void wconv64(
    const float* __restrict__ W, short* __restrict__ Wt,
    int K, int N, size_t in_lstride, size_t out_lstride)
{
  __shared__ float t[64][65];
  const int n0 = blockIdx.x * 64, k0 = blockIdx.y * 64;
  const float* Wl = W + (size_t)blockIdx.z * in_lstride;
  short* Wtl = Wt + (size_t)blockIdx.z * out_lstride;
  const int tid = threadIdx.x;
  const int c4 = (tid & 15) * 4, r = tid >> 4;
  #pragma unroll
  for (int i = 0; i < 4; ++i){
    const float4 v = *(const float4*)(Wl + (size_t)(k0 + r + i*16) * N + n0 + c4);
    t[r + i*16][c4 + 0] = v.x;
    t[r + i*16][c4 + 1] = v.y;
    t[r + i*16][c4 + 2] = v.z;
    t[r + i*16][c4 + 3] = v.w;
  }
  __syncthreads();
  #pragma unroll
  for (int i = 0; i < 4; ++i){
    const int n = r + i*16;
    short4 s;
    s.x = f2bf(t[c4 + 0][n]);
    s.y = f2bf(t[c4 + 1][n]);
    s.z = f2bf(t[c4 + 2][n]);
    s.w = f2bf(t[c4 + 3][n]);
    *(short4*)(Wtl + (size_t)(n0 + n) * K + k0 + c4) = s;
  }
}

// ---------------------------------------------------------------- GEMM
// 512 threads = 8 waves (2M x 4N), tile 128x128, per-wave 64x32 output.
// 2 LDS buffers (64 KB -> 2 blocks/CU = 4 waves/SIMD), canonical 2-phase:
//   STAGE(next buf) ; compute(cur) ; vmcnt(0) ; s_barrier
// T2 XOR-swizzle via pre-swizzled global source col (gload_lds dest linear),
// read-side applies the same XOR. T1 XCD swizzle on the 2D slice.
// Split-K via blockIdx.z * kchunk (EPI 3 writes raw fp32 partials).
// EPI 0: bf16 = acc + qkv-bias(b0/b1/b2 by 1024-col segment)
// EPI 2: bf16 = gelu(acc + b0[col])
// EPI 3: fp32 partial (no bias) at out + z*M*N
template<int EPI>
__global__ __launch_bounds__(512, 4) void gemm2(
    const short* __restrict__ A, const short* __restrict__ Bt,
    void* __restrict__ out,
    const float* __restrict__ b0, const float* __restrict__ b1,
    const float* __restrict__ b2, int M, int N, int K, int kchunk)
{
  __shared__ __attribute__((aligned(16))) short a_t[2][128 * 64];
  __shared__ __attribute__((aligned(16))) short b_t[2][128 * 64];
  const int tid = threadIdx.x, l = tid & 63, w = tid >> 6;

  const int gx = gridDim.x;
  const int bid = blockIdx.y * gx + blockIdx.x;
  const int cpx = (gx * gridDim.y) >> 3;
  const int swz = (bid & 7) * cpx + (bid >> 3);
  const int m0 = (swz / gx) * 128, n0 = (swz % gx) * 128;
  const int kt0 = blockIdx.z * kchunk;

  const int lr = l >> 3;                        // staging row within 8-group
  const int scol = ((l & 7) * 16) ^ (lr << 4);  // pre-swizzled source byte col
  const int wm = w >> 2, wn = w & 3;            // wave grid 2x4
  const int fr = l & 15;
  const int rxor = (fr & 7) << 4;               // read-side XOR (bytes)

  const v4f vz = {0.f, 0.f, 0.f, 0.f};
  v4f acc[4][2];
  #pragma unroll
  for (int i = 0; i < 4; ++i){ acc[i][0] = vz; acc[i][1] = vz; }

  const char* Ab = (const char*)A;
  const char* Bb = (const char*)Bt;
  auto stage = [&](int buf, int kt){
    #pragma unroll
    for (int j = 0; j < 2; ++j){
      const int rb = w * 16 + j * 8;
      gload16(Ab + ((size_t)(m0 + rb + lr) * K + kt) * 2 + scol,
              (char*)a_t[buf] + rb * 128);
      gload16(Bb + ((size_t)(n0 + rb + lr) * K + kt) * 2 + scol,
              (char*)b_t[buf] + rb * 128);
    }
  };

  const int NT = kchunk >> 6;
  stage(0, kt0);
  asm volatile("s_waitcnt vmcnt(0)" ::: "memory");
  __builtin_amdgcn_s_barrier();

  for (int t = 0; t < NT; ++t){
    if (t + 1 < NT) stage((t + 1) & 1, kt0 + ((t + 1) << 6));
    const char* ab = (const char*)a_t[t & 1];
    const char* bb = (const char*)b_t[t & 1];
    #pragma unroll
    for (int ks = 0; ks < 2; ++ks){
      const int co = ks * 64 + (l >> 4) * 16;
      v8s af[4], bf[2];
      #pragma unroll
      for (int mf = 0; mf < 4; ++mf)
        af[mf] = *(const v8s*)(ab + (wm * 64 + mf * 16 + fr) * 128 + (co ^ rxor));
      #pragma unroll
      for (int nf = 0; nf < 2; ++nf)
        bf[nf] = *(const v8s*)(bb + (wn * 32 + nf * 16 + fr) * 128 + (co ^ rxor));
      #pragma unroll
      for (int mf = 0; mf < 4; ++mf)
        #pragma unroll
        for (int nf = 0; nf < 2; ++nf)
          acc[mf][nf] = __builtin_amdgcn_mfma_f32_16x16x32_bf16(
              af[mf], bf[nf], acc[mf][nf], 0, 0, 0);
    }
    asm volatile("s_waitcnt vmcnt(0)" ::: "memory");
    __builtin_amdgcn_s_barrier();
  }

  float* outp = (EPI == 3)
      ? (float*)out + (size_t)blockIdx.z * ((size_t)M * N) : (float*)out;
  #pragma unroll
  for (int mf = 0; mf < 4; ++mf){
    #pragma unroll
    for (int nf = 0; nf < 2; ++nf){
      const int col = n0 + wn * 32 + nf * 16 + fr;
      float bias = 0.f;
      if (EPI == 0)
        bias = col < 1024 ? b0[col] : (col < 2048 ? b1[col - 1024] : b2[col - 2048]);
      else if (EPI == 2)
        bias = b0[col];
      #pragma unroll
      for (int r = 0; r < 4; ++r){
        const int row = m0 + wm * 64 + mf * 16 + (l >> 4) * 4 + r;
        const float v = acc[mf][nf][r] + bias;
        if (EPI == 0){
          ((short*)out)[(size_t)row * N + col] = f2bf(v);
        } else if (EPI == 2){
          const float g = 0.5f * v * (1.0f + erff(v * 0.70710678118f));
          ((short*)out)[(size_t)row * N + col] = f2bf(g);
        } else {
          outp[(size_t)row * N + col] = v;
        }
      }
    }
  }
}

// ---------------------------------------------------------------- Attention
// (unchanged from R4)
__global__ __launch_bounds__(256) void attn_kernel(
    const short* __restrict__ qkv, short* __restrict__ y)
{
  const int qb = blockIdx.x, hh = blockIdx.y, b = blockIdx.z;
  const int tid = threadIdx.x, l = tid & 63, w = tid >> 6;
  __shared__ __attribute__((aligned(16))) short vt[2][64 * 72];
  __shared__ __attribute__((aligned(16))) short pl[4][16 * 72];

  const int fr = l & 15;
  const int fko = (l >> 4) * 8;
  const size_t qrow = (size_t)(b * 1024 + qb * 64 + w * 16 + fr) * 3072 + hh * 64 + fko;
  v8s qf0, qf1;
  {
    const v8s q0 = *(const v8s*)(qkv + qrow);
    const v8s q1 = *(const v8s*)(qkv + qrow + 32);
    #pragma unroll
    for (int j = 0; j < 8; ++j){
      qf0[j] = f2bf(bf2f(q0[j]) * 0.125f);
      qf1[j] = f2bf(bf2f(q1[j]) * 0.125f);
    }
  }

  const v4f vz = {0.f, 0.f, 0.f, 0.f};
  v4f o[4] = {vz, vz, vz, vz};
  float mrow[4] = {-1e30f, -1e30f, -1e30f, -1e30f};
  float lrow[4] = {0.f, 0.f, 0.f, 0.f};

  const int vd0 = (tid & 7) * 8, vs0 = (tid >> 3) * 2;
  const short* kbase = qkv + (size_t)(b * 1024) * 3072 + 1024 + hh * 64 + fko;

  for (int kvb = 0; kvb <= qb; ++kvb){
    short* vcur = vt[kvb & 1];
    {
      const short* vsrc = qkv + (size_t)(b * 1024 + kvb * 64 + vs0) * 3072
                          + 2048 + hh * 64 + vd0;
      const v8s r0 = *(const v8s*)vsrc;
      const v8s r1 = *(const v8s*)(vsrc + 3072);
      #pragma unroll
      for (int j = 0; j < 8; ++j){
        const uint32_t pk = (uint16_t)r0[j] | ((uint32_t)(uint16_t)r1[j] << 16);
        *(uint32_t*)(vcur + (vd0 + j) * 72 + vs0) = pk;
      }
    }
    __syncthreads();

    v4f s[4] = {vz, vz, vz, vz};
    #pragma unroll
    for (int nf = 0; nf < 4; ++nf){
      const short* kp = kbase + (size_t)(kvb * 64 + nf * 16 + fr) * 3072;
      const v8s kb0 = *(const v8s*)kp;
      const v8s kb1 = *(const v8s*)(kp + 32);
      s[nf] = __builtin_amdgcn_mfma_f32_16x16x32_bf16(qf0, kb0, s[nf], 0, 0, 0);
      s[nf] = __builtin_amdgcn_mfma_f32_16x16x32_bf16(qf1, kb1, s[nf], 0, 0, 0);
    }

    #pragma unroll
    for (int r = 0; r < 4; ++r){
      float mx = fmaxf(fmaxf(s[0][r], s[1][r]), fmaxf(s[2][r], s[3][r]));
      mx = fmaxf(mx, __shfl_xor(mx, 1));
      mx = fmaxf(mx, __shfl_xor(mx, 2));
      mx = fmaxf(mx, __shfl_xor(mx, 4));
      mx = fmaxf(mx, __shfl_xor(mx, 8));
      const float mn = fmaxf(mrow[r], mx);
      const float fac = __expf(mrow[r] - mn);
      float rs = 0.f;
      #pragma unroll
      for (int nf = 0; nf < 4; ++nf){ s[nf][r] = __expf(s[nf][r] - mn); rs += s[nf][r]; }
      rs += __shfl_xor(rs, 1);
      rs += __shfl_xor(rs, 2);
      rs += __shfl_xor(rs, 4);
      rs += __shfl_xor(rs, 8);
      lrow[r] = lrow[r] * fac + rs;
      mrow[r] = mn;
      #pragma unroll
      for (int nf = 0; nf < 4; ++nf) o[nf][r] *= fac;
    }

    #pragma unroll
    for (int nf = 0; nf < 4; ++nf)
      #pragma unroll
      for (int r = 0; r < 4; ++r)
        pl[w][((l >> 4) * 4 + r) * 72 + nf * 16 + fr] = f2bf(s[nf][r]);

    #pragma unroll
    for (int ks = 0; ks < 2; ++ks){
      const v8s pa = *(const v8s*)(pl[w] + fr * 72 + ks * 32 + fko);
      #pragma unroll
      for (int nf = 0; nf < 4; ++nf){
        const v8s vb = *(const v8s*)(vcur + (nf * 16 + fr) * 72 + ks * 32 + fko);
        o[nf] = __builtin_amdgcn_mfma_f32_16x16x32_bf16(pa, vb, o[nf], 0, 0, 0);
      }
    }
  }

  #pragma unroll
  for (int r = 0; r < 4; ++r){
    const float inv = 1.0f / lrow[r];
    #pragma unroll
    for (int nf = 0; nf < 4; ++nf) o[nf][r] *= inv;
  }
  #pragma unroll
  for (int nf = 0; nf < 4; ++nf)
    #pragma unroll
    for (int r = 0; r < 4; ++r){
      const int row = b * 1024 + qb * 64 + w * 16 + (l >> 4) * 4 + r;
      y[(size_t)row * 1024 + hh * 64 + nf * 16 + fr] = f2bf(o[nf][r]);
    }
}

// ---------------------------------------------------------------- launch
extern "C" void kernel_launch(void* const* d_in, const int* in_sizes, int n_in,
                              void* d_out, int out_size, void* d_ws, size_t ws_size,
                              hipStream_t stream)
{
  const float* seq  = (const float*)d_in[0];
  const float* ln1w = (const float*)d_in[1];
  const float* ln1b = (const float*)d_in[2];
  const float* Wq   = (const float*)d_in[3];
  const float* bq   = (const float*)d_in[4];
  const float* Wk   = (const float*)d_in[5];
  const float* bk   = (const float*)d_in[6];
  const float* Wv   = (const float*)d_in[7];
  const float* bv   = (const float*)d_in[8];
  const float* Wp   = (const float*)d_in[9];
  const float* bp   = (const float*)d_in[10];
  const float* ln2w = (const float*)d_in[11];
  const float* ln2b = (const float*)d_in[12];
  const float* W1   = (const float*)d_in[13];
  const float* b1   = (const float*)d_in[14];
  const float* W2   = (const float*)d_in[15];
  const float* b2   = (const float*)d_in[16];
  const float* lnfw = (const float*)d_in[17];
  const float* lnfb = (const float*)d_in[18];

  char* p = (char*)d_ws;
  auto carve = [&](size_t bytes){
    void* r = (void*)p;
    p += (bytes + 255) & ~(size_t)255;
    return r;
  };
  short* wtQKV = (short*)carve((size_t)8 * 3072 * 1024 * 2);
  short* wtP   = (short*)carve((size_t)8 * 1024 * 1024 * 2);
  short* wt1   = (short*)carve((size_t)8 * 4096 * 1024 * 2);
  short* wt2   = (short*)carve((size_t)8 * 1024 * 4096 * 2);
  float* x     = (float*)carve((size_t)2048 * 1024 * 4);
  short* h     = (short*)carve((size_t)2048 * 1024 * 2);
  short* qkv   = (short*)carve((size_t)2048 * 3072 * 2);
  short* y     = (short*)carve((size_t)2048 * 1024 * 2);
  short* hm    = (short*)carve((size_t)2048 * 4096 * 2);
  float* part  = (float*)carve((size_t)4 * 2048 * 1024 * 4);   // split-K partials

  const size_t S1M = (size_t)1024 * 1024, S3M = (size_t)3072 * 1024,
               S4M = (size_t)4096 * 1024;

  wconv64<<<dim3(16, 16, 8), 256, 0, stream>>>(Wq, wtQKV,            1024, 1024, S1M, S3M);
  wconv64<<<dim3(16, 16, 8), 256, 0, stream>>>(Wk, wtQKV + S1M,      1024, 1024, S1M, S3M);
  wconv64<<<dim3(16, 16, 8), 256, 0, stream>>>(Wv, wtQKV + 2 * S1M,  1024, 1024, S1M, S3M);
  wconv64<<<dim3(16, 16, 8), 256, 0, stream>>>(Wp, wtP,              1024, 1024, S1M, S1M);
  wconv64<<<dim3(64, 16, 8), 256, 0, stream>>>(W1, wt1,              1024, 4096, S4M, S4M);
  wconv64<<<dim3(16, 64, 8), 256, 0, stream>>>(W2, wt2,              4096, 1024, S4M, S4M);

  ln_kernel<<<2048, 256, 0, stream>>>(seq, ln1w, ln1b, h);

  for (int l = 0; l < 8; ++l){
    const float* xin = (l == 0) ? seq : x;
    // QKV projection (direct, bf16 out + bias)
    gemm2<0><<<dim3(24, 16, 1), 512, 0, stream>>>(
        h, wtQKV + l * S3M, qkv, bq + l * 1024, bk + l * 1024, bv + l * 1024,
        2048, 3072, 1024, 1024);
    attn_kernel<<<dim3(16, 16, 2), 256, 0, stream>>>(qkv, y);
    // P projection: split-K 2 -> partials; reduce fused with ln2 -> x, h
    gemm2<3><<<dim3(8, 16, 2), 512, 0, stream>>>(
        y, wtP + l * S1M, part, nullptr, nullptr, nullptr,
        2048, 1024, 1024, 512);
    reduce_ln<2, false><<<2048, 256, 0, stream>>>(
        part, xin, bp + l * 1024, x, ln2w + l * 1024, ln2b + l * 1024, h);
    // MLP1 (direct, gelu bf16 out)
    gemm2<2><<<dim3(32, 16, 1), 512, 0, stream>>>(
        h, wt1 + l * S4M, hm, b1 + l * 4096, nullptr, nullptr,
        2048, 4096, 1024, 1024);
    // MLP2: split-K 4 -> partials; reduce fused with next ln1 (or final lnf)
    gemm2<3><<<dim3(8, 16, 4), 512, 0, stream>>>(
        hm, wt2 + l * S4M, part, nullptr, nullptr, nullptr,
        2048, 1024, 4096, 1024);
    if (l < 7){
      reduce_ln<4, false><<<2048, 256, 0, stream>>>(
          part, x, b2 + l * 1024, x, ln1w + (l + 1) * 1024,
          ln1b + (l + 1) * 1024, h);
    } else {
      reduce_ln<4, true><<<2048, 256, 0, stream>>>(
          part, x, b2 + l * 1024, x, lnfw, lnfb, d_out);
    }
  }
}